// Round 3
// baseline (732.605 us; speedup 1.0000x reference)
//
#include <hip/hip_runtime.h>
#include <math.h>

#define NS 131072
#define NFR 128
#define CPDIM 16
#define WIN 1024
#define NVOICE 8
#define NBLK 3
#define NCP 512
#define NVERB 8
#define NEV 64
#define N1 1024          // complex FFT length (real length 2048)
#define NBINS 1025
#define NBP 1032         // padded row stride (float2) -> 8256 B, 64B-aligned rows
#define IDX(i) ((i) + ((i) >> 5))

struct EvParams {
  int vidx, cpidx, ridx;
  float vm0, vm1, amp;
  float mixw0, mixw1, mixw2;
  unsigned int maxslot;
  int pad[6];
}; // 64 bytes

// ============================== K_tw: twiddle table e^{-2pi i k/2048}, k=0..1023 ==============================
__global__ void kt_tw(float2* __restrict__ tw) {
  int k = blockIdx.x * 256 + threadIdx.x;
  if (k < 1024) {
    float ang = -3.067961575771282340e-03f * (float)k; // -2pi/2048
    float s, c;
    sincosf(ang, &s, &c);
    tw[k] = make_float2(c, s);
  }
}

// ============================== Kz: zero-init output ==============================
__global__ __launch_bounds__(256) void kz_zero(float4* __restrict__ out4) {
  size_t i = (size_t)blockIdx.x * 256 + threadIdx.x;
  out4[i] = make_float4(0.f, 0.f, 0.f, 0.f);
}

// ============================== FFT-1024 stages (in-place, bit-reversed input, padded idx) ==============================
__device__ __forceinline__ void fft1024(float* re, float* im,
                                        const float* twr, const float* twi,
                                        int tid, bool inverse) {
  #pragma unroll
  for (int s = 1; s <= 10; ++s) {
    const int half = 1 << (s - 1);
    const int tsh = 11 - s;
    for (int k = tid; k < 512; k += 256) {
      int j = k & (half - 1);
      int i0 = ((k ^ j) << 1) | j;
      int i1 = IDX(i0 + half);
      i0 = IDX(i0);
      float wr = twr[j << tsh];
      float wi = twi[j << tsh];
      if (inverse) wi = -wi;
      float xr = re[i1], xi = im[i1];
      float tr = wr * xr - wi * xi;
      float ti = wr * xi + wi * xr;
      float ur = re[i0], ui = im[i0];
      re[i0] = ur + tr; im[i0] = ui + ti;
      re[i1] = ur - tr; im[i1] = ui - ti;
    }
    __syncthreads();
  }
}

// real-2048 forward FFT via packed complex-1024
__device__ __forceinline__ void rfft_fwd(const float2* __restrict__ src2, float scale,
                                         float2* __restrict__ dst,
                                         float* re, float* im, float* twr, float* twi,
                                         const float2* __restrict__ twg, int tid) {
  for (int i = tid; i < 1024; i += 256) { float2 w = twg[i]; twr[i] = w.x; twi[i] = w.y; }
  for (int n = tid; n < 1024; n += 256) {
    int r = IDX(__brev(n) >> 22);
    if (n < 512) {
      float2 x = src2[n];
      re[r] = x.x * scale; im[r] = x.y * scale;
    } else { re[r] = 0.0f; im[r] = 0.0f; }
  }
  __syncthreads();
  fft1024(re, im, twr, twi, tid, false);
  // untwist: X[k] = A + W_k B, W_k = e^{-i pi k/1024}
  for (int k = tid; k <= 1024; k += 256) {
    int km = (1024 - k) & 1023;
    float zr = re[IDX(k & 1023)], zi = im[IDX(k & 1023)];
    float mr = re[IDX(km)], mi = im[IDX(km)];
    float Are = 0.5f * (zr + mr), Aim = 0.5f * (zi - mi);
    float Bre = 0.5f * (zi + mi), Bim = 0.5f * (mr - zr);
    float wr, wi;
    if (k == 1024) { wr = -1.0f; wi = 0.0f; }
    else { wr = twr[k]; wi = twi[k]; }
    dst[k] = make_float2(Are + wr * Bre - wi * Bim, Aim + wr * Bim + wi * Bre);
  }
}

// ============================== K0: per-event params ==============================
__global__ void k0_params(const float* __restrict__ voice, const float* __restrict__ cpc,
                          const float* __restrict__ amps, const float* __restrict__ roomc,
                          const float* __restrict__ roomm, const float* __restrict__ mix,
                          EvParams* __restrict__ P) {
  int e = blockIdx.x;
  int tid = threadIdx.x; // 64 threads
  __shared__ float bvals[64];
  __shared__ int bidx[64];

  if (tid == 0) {
    const float* v = voice + e * NVOICE;
    int vi = 0; float bv = v[0];
    for (int i = 1; i < NVOICE; ++i) if (v[i] > bv) { bv = v[i]; vi = i; }
    P[e].vidx = vi;

    const float* r = roomc + e * NVERB;
    int ri = 0; float br = r[0];
    for (int i = 1; i < NVERB; ++i) if (r[i] > br) { br = r[i]; ri = i; }
    P[e].ridx = ri;

    float m0 = roomm[e * 2 + 0], m1 = roomm[e * 2 + 1];
    float mx = fmaxf(m0, m1);
    float e0 = expf(m0 - mx), e1 = expf(m1 - mx);
    float inv = 1.0f / (e0 + e1);
    P[e].vm0 = e0 * inv;
    P[e].vm1 = e1 * inv;
    P[e].amp = fabsf(amps[e]);

    const float* mm = mix + vi * NBLK;
    float mmx = fmaxf(fmaxf(mm[0], mm[1]), mm[2]);
    float w0 = expf(mm[0] - mmx), w1 = expf(mm[1] - mmx), w2 = expf(mm[2] - mmx);
    float si = 1.0f / (w0 + w1 + w2);
    P[e].mixw0 = w0 * si; P[e].mixw1 = w1 * si; P[e].mixw2 = w2 * si;
    P[e].maxslot = 0u;
  }

  const float* c = cpc + (size_t)e * NCP;
  float bv = -INFINITY; int bi = 0;
  for (int i = tid; i < NCP; i += 64) {
    float x = c[i];
    if (x > bv) { bv = x; bi = i; }
  }
  bvals[tid] = bv; bidx[tid] = bi;
  __syncthreads();
  if (tid == 0) {
    float best = bvals[0]; int besti = bidx[0];
    for (int i = 1; i < 64; ++i) {
      if (bvals[i] > best || (bvals[i] == best && bidx[i] < besti)) { best = bvals[i]; besti = bidx[i]; }
    }
    P[e].cpidx = besti;
  }
}

// ============================== Kv: verb chunk FFTs ==============================
__global__ __launch_bounds__(256) void kv_fft(const float* __restrict__ verbs,
                                              const float2* __restrict__ twg,
                                              float2* __restrict__ Vhat) {
  __shared__ float re[N1 + 32], im[N1 + 32];
  __shared__ float twr[N1], twi[N1];
  int v = blockIdx.x >> 7, j = blockIdx.x & 127;
  int tid = threadIdx.x;
  rfft_fwd((const float2*)(verbs + (size_t)v * NS + j * WIN), 1.0f,
           Vhat + ((size_t)v * NFR + j) * NBP, re, im, twr, twi, twg, tid);
}

// ============================== K1a: recurrent synthesis ==============================
__global__ __launch_bounds__(256) void k1a_synth(const float* __restrict__ cp_items,
                                                 const float* __restrict__ w1_all,
                                                 const float* __restrict__ w2_all,
                                                 const float* __restrict__ decays,
                                                 const float* __restrict__ gains,
                                                 const EvParams* __restrict__ P,
                                                 float* __restrict__ cp_out_all) {
  __shared__ float wc[2048], xb[2048], yb[2048];
  __shared__ float w1s[256], w2s[256];
  __shared__ float dv[16], gv[16];
  __shared__ float rv[4];
  __shared__ int ri[4];
  __shared__ float s_scale;

  int e = blockIdx.x, tid = threadIdx.x;
  int vidx = P[e].vidx, cpidx = P[e].cpidx;
  int base = tid * 8;

  // load 8 values/thread into registers + block sum
  float vals[8];
  float ls = 0.0f;
  #pragma unroll
  for (int q = 0; q < 8; ++q) {
    float x = cp_items[(size_t)cpidx * 2048 + base + q];
    vals[q] = x; ls += x;
  }
  #pragma unroll
  for (int off = 32; off > 0; off >>= 1) ls += __shfl_xor(ls, off);
  if ((tid & 63) == 0) rv[tid >> 6] = ls;
  __syncthreads();
  if (tid == 0) s_scale = 1.0f / (rv[0] + rv[1] + rv[2] + rv[3] + 1e-8f);
  for (int i = tid; i < 2048; i += 256) wc[i] = 0.0f;
  __syncthreads();
  float scale = s_scale;

  // top-32 selection (register-resident, shuffle argmax, first-index tiebreak)
  for (int it = 0; it < 32; ++it) {
    float bv = -1.0f; int bi = 1 << 30;
    #pragma unroll
    for (int q = 0; q < 8; ++q) {
      if (vals[q] > bv) { bv = vals[q]; bi = base + q; }
    }
    #pragma unroll
    for (int off = 32; off > 0; off >>= 1) {
      float ov = __shfl_xor(bv, off); int oi = __shfl_xor(bi, off);
      if (ov > bv || (ov == bv && oi < bi)) { bv = ov; bi = oi; }
    }
    if ((tid & 63) == 0) { rv[tid >> 6] = bv; ri[tid >> 6] = bi; }
    __syncthreads();
    float wv = rv[0]; int wi = ri[0];
    #pragma unroll
    for (int w = 1; w < 4; ++w) {
      if (rv[w] > wv || (rv[w] == wv && ri[w] < wi)) { wv = rv[w]; wi = ri[w]; }
    }
    if ((wi >> 3) == tid) { vals[wi & 7] = -2.0f; wc[wi] = wv * scale; }
    __syncthreads();
  }

  for (int l = 0; l < NBLK; ++l) {
    int wbase = (vidx * NBLK + l) * 256;
    w1s[tid] = w1_all[wbase + tid];
    w2s[tid] = w2_all[wbase + tid];
    if (tid < 16) {
      float dp = decays[(vidx * NBLK + l) * 16 + tid];
      float sd = 1.0f / (1.0f + expf(-dp));
      dv[tid] = 1e-12f + 0.5f + 0.5f * sd;
      float gp = gains[(vidx * NBLK + l) * 16 + tid];
      gv[tid] = 5.0f / (1.0f + expf(-gp));
    }
    __syncthreads();
    for (int i = tid; i < 2048; i += 256) {
      int cch = i >> 7, f = i & 127;
      float acc = 0.0f;
      #pragma unroll
      for (int k = 0; k < 16; ++k) acc += w1s[cch * 16 + k] * fmaxf(wc[k * 128 + f], 0.0f);
      xb[i] = acc;
    }
    __syncthreads();
    if (tid < 16) {
      float a = 0.0f, d = dv[tid];
      for (int t = 0; t < 128; ++t) { a = d * (a + xb[tid * 128 + t]); yb[tid * 128 + t] = a; }
    }
    __syncthreads();
    for (int i = tid; i < 2048; i += 256) {
      int cch = i >> 7, f = i & 127;
      float acc = xb[i];
      #pragma unroll
      for (int k = 0; k < 16; ++k) acc += w2s[cch * 16 + k] * yb[k * 128 + f];
      float co = tanhf(acc * gv[cch]);
      wc[i] = co;
      cp_out_all[((size_t)e * NBLK + l) * 2048 + i] = co;
    }
    __syncthreads();
  }
}

// ============================== K1b: audio matmul + mix + maxabs ==============================
__global__ __launch_bounds__(256) void k1b_audio(const float* __restrict__ amaps,
                                                 const float* __restrict__ cp_out_all,
                                                 EvParams* __restrict__ P,
                                                 float* __restrict__ mixed) {
  __shared__ float cps[NBLK][16][16]; // [bl][c][fl]
  __shared__ float red[256];
  int e = blockIdx.x >> 3, fg = blockIdx.x & 7;
  int f0 = fg * 16, tid = threadIdx.x;
  int vidx = P[e].vidx;
  float mw[3] = {P[e].mixw0, P[e].mixw1, P[e].mixw2};

  for (int i = tid; i < NBLK * 256; i += 256) {
    int bl = i >> 8, r = i & 255, cch = r >> 4, fl = r & 15;
    cps[bl][cch][fl] = cp_out_all[((size_t)e * NBLK + bl) * 2048 + cch * 128 + f0 + fl];
  }
  __syncthreads();

  float amax = 0.0f;
  for (int jw = 0; jw < 4; ++jw) {
    int w = jw * 256 + tid;
    float am[NBLK][16];
    #pragma unroll
    for (int bl = 0; bl < NBLK; ++bl) {
      const float* ap = amaps + (((size_t)(vidx * NBLK + bl)) * WIN + w) * CPDIM;
      #pragma unroll
      for (int cch = 0; cch < 16; ++cch) am[bl][cch] = ap[cch] * mw[bl];
    }
    for (int fl = 0; fl < 16; ++fl) {
      float acc = 0.0f;
      #pragma unroll
      for (int bl = 0; bl < NBLK; ++bl)
        #pragma unroll
        for (int cch = 0; cch < 16; ++cch) acc += am[bl][cch] * cps[bl][cch][fl];
      mixed[(size_t)e * NS + (size_t)(f0 + fl) * WIN + w] = acc;
      amax = fmaxf(amax, fabsf(acc));
    }
  }
  red[tid] = amax;
  __syncthreads();
  for (int s = 128; s > 0; s >>= 1) { if (tid < s) red[tid] = fmaxf(red[tid], red[tid + s]); __syncthreads(); }
  if (tid == 0) atomicMax(&P[e].maxslot, __float_as_uint(red[0]));
}

// ============================== K2: forward chunk FFTs (scaled by 1/(max+1e-8)) ==============================
__global__ __launch_bounds__(256) void k2_fwd(const float* __restrict__ mixed,
                                              const EvParams* __restrict__ P,
                                              const float2* __restrict__ twg,
                                              float2* __restrict__ Shat) {
  __shared__ float re[N1 + 32], im[N1 + 32];
  __shared__ float twr[N1], twi[N1];
  int e = blockIdx.x >> 7, p = blockIdx.x & 127;
  int tid = threadIdx.x;
  float invn = 1.0f / (__uint_as_float(P[e].maxslot) + 1e-8f);
  rfft_fwd((const float2*)(mixed + (size_t)e * NS + p * WIN), invn,
           Shat + ((size_t)e * NFR + p) * NBP, re, im, twr, twi, twg, tid);
}

// ============================== K3: double triangular conv in chunk-frequency domain ==============================
// 16 bins/block, float2 LDS padded to stride 17 (bank-pair conflict-free)
__global__ __launch_bounds__(256, 4) void k3_conv(const float2* __restrict__ Shat,
                                                  const float2* __restrict__ Vhat,
                                                  const float* __restrict__ times_g,
                                                  const EvParams* __restrict__ P,
                                                  float2* __restrict__ Ohat) {
  __shared__ float2 S2[128 * 17];
  __shared__ float2 V2[128 * 17]; // reused as U after first conv
  __shared__ float tms[128];

  int bx = blockIdx.x;
  int e = bx / 65, bg = bx % 65;
  int bin0 = bg * 16;
  int tid = threadIdx.x;
  int b = tid & 15, pg = tid >> 4;
  int p0 = pg * 8;

  int ridx = P[e].ridx;
  float vm0 = P[e].vm0, vm1 = P[e].vm1, amp = P[e].amp;

  const float2* Sg = Shat + (size_t)e * NFR * NBP;
  const float2* Vg = Vhat + (size_t)ridx * NFR * NBP;
  for (int i = tid; i < 2048; i += 256) {
    int f = i >> 4, bb = i & 15;
    int bin = bin0 + bb; if (bin > 1024) bin = 1024;
    S2[f * 17 + bb] = Sg[f * NBP + bin];
    V2[f * 17 + bb] = Vg[f * NBP + bin];
  }
  if (tid < 128) tms[tid] = times_g[e * NFR + tid];
  __syncthreads();

  // -------- first conv: G_p = sum_{f=0..p} S_f * V_{p-f}, p in [p0, p0+8) --------
  float ar[8], ai[8];
  #pragma unroll
  for (int t = 0; t < 8; ++t) { ar[t] = 0.0f; ai[t] = 0.0f; }

  for (int ft = 0; ft < pg; ++ft) {
    int f0v = ft * 8;
    float2 s[8];
    #pragma unroll
    for (int ff = 0; ff < 8; ++ff) s[ff] = S2[(f0v + ff) * 17 + b];
    float2 v[15];
    int jb = p0 - f0v - 7;
    #pragma unroll
    for (int m = 0; m < 15; ++m) v[m] = V2[(jb + m) * 17 + b];
    #pragma unroll
    for (int ff = 0; ff < 8; ++ff) {
      #pragma unroll
      for (int t = 0; t < 8; ++t) {
        int m = 7 - ff + t;
        ar[t] += s[ff].x * v[m].x - s[ff].y * v[m].y;
        ai[t] += s[ff].x * v[m].y + s[ff].y * v[m].x;
      }
    }
  }
  { // diagonal tile f in [p0, p0+7], constraint f <= p
    float2 s[8];
    #pragma unroll
    for (int ff = 0; ff < 8; ++ff) s[ff] = S2[(p0 + ff) * 17 + b];
    float2 v[8];
    #pragma unroll
    for (int m = 0; m < 8; ++m) v[m] = V2[m * 17 + b];
    #pragma unroll
    for (int ff = 0; ff < 8; ++ff) {
      #pragma unroll
      for (int t = 0; t < 8; ++t) {
        if (t >= ff) {
          int m = t - ff;
          ar[t] += s[ff].x * v[m].x - s[ff].y * v[m].y;
          ai[t] += s[ff].x * v[m].y + s[ff].y * v[m].x;
        }
      }
    }
  }

  // -------- U_p = amp*(vm0*G_p + vm1*S_p); store into V's LDS --------
  __syncthreads();
  #pragma unroll
  for (int t = 0; t < 8; ++t) {
    int p = p0 + t;
    float2 sv = S2[p * 17 + b];
    V2[p * 17 + b] = make_float2(amp * (vm0 * ar[t] + vm1 * sv.x),
                                 amp * (vm0 * ai[t] + vm1 * sv.y));
  }
  __syncthreads();

  // -------- second conv: O_p = sum_{r=0..p} times[r] * U_{p-r} --------
  #pragma unroll
  for (int t = 0; t < 8; ++t) { ar[t] = 0.0f; ai[t] = 0.0f; }

  for (int ft = 0; ft < pg; ++ft) {
    int f0v = ft * 8;
    float trr[8];
    #pragma unroll
    for (int ff = 0; ff < 8; ++ff) trr[ff] = tms[f0v + ff];
    float2 u[15];
    int jb = p0 - f0v - 7;
    #pragma unroll
    for (int m = 0; m < 15; ++m) u[m] = V2[(jb + m) * 17 + b];
    #pragma unroll
    for (int ff = 0; ff < 8; ++ff) {
      #pragma unroll
      for (int t = 0; t < 8; ++t) {
        int m = 7 - ff + t;
        ar[t] += trr[ff] * u[m].x;
        ai[t] += trr[ff] * u[m].y;
      }
    }
  }
  { // diagonal
    float trr[8];
    #pragma unroll
    for (int ff = 0; ff < 8; ++ff) trr[ff] = tms[p0 + ff];
    float2 u[8];
    #pragma unroll
    for (int m = 0; m < 8; ++m) u[m] = V2[m * 17 + b];
    #pragma unroll
    for (int ff = 0; ff < 8; ++ff) {
      #pragma unroll
      for (int t = 0; t < 8; ++t) {
        if (t >= ff) {
          int m = t - ff;
          ar[t] += trr[ff] * u[m].x;
          ai[t] += trr[ff] * u[m].y;
        }
      }
    }
  }

  int bin = bin0 + b;
  if (bin <= 1024) {
    float2* Og = Ohat + (size_t)e * NFR * NBP;
    #pragma unroll
    for (int t = 0; t < 8; ++t) {
      Og[(p0 + t) * NBP + bin] = make_float2(ar[t], ai[t]);
    }
  }
}

// ============================== K4: inverse real FFT + overlap-add via atomics ==============================
__global__ __launch_bounds__(256) void k4_ifft(const float2* __restrict__ Ohat,
                                               const float2* __restrict__ twg,
                                               float* __restrict__ out) {
  __shared__ float re[N1 + 32], im[N1 + 32];
  __shared__ float twr[N1], twi[N1];
  int e = blockIdx.x >> 7, p = blockIdx.x & 127;
  int tid = threadIdx.x;
  const float2* src = Ohat + ((size_t)e * NFR + p) * NBP;
  for (int i = tid; i < 1024; i += 256) { float2 w = twg[i]; twr[i] = w.x; twi[i] = w.y; }
  __syncthreads();
  // twist: Z[k] = A + iB
  for (int k = tid; k < 1024; k += 256) {
    float2 Xk = src[k];
    float2 Xm = src[1024 - k];
    float Are = 0.5f * (Xk.x + Xm.x), Aim = 0.5f * (Xk.y - Xm.y);
    float Dre = 0.5f * (Xk.x - Xm.x), Dim = 0.5f * (Xk.y + Xm.y);
    float wr = twr[k], wi = twi[k];
    float Bre = wr * Dre + wi * Dim;
    float Bim = wr * Dim - wi * Dre;
    int r = IDX(__brev(k) >> 22);
    re[r] = Are - Bim;
    im[r] = Aim + Bre;
  }
  __syncthreads();
  fft1024(re, im, twr, twi, tid, true);
  const float inv = 1.0f / (float)N1;
  // time sample 2n = re[n], 2n+1 = im[n]; chunk output covers samples [p*1024, p*1024+2047]
  float* o = out + (size_t)e * NS + (size_t)p * WIN;
  int nmax = (p == 127) ? 512 : 1024; // drop final tail beyond NS
  for (int n = tid; n < nmax; n += 256) {
    atomicAdd(&o[2 * n],     re[IDX(n)] * inv);
    atomicAdd(&o[2 * n + 1], im[IDX(n)] * inv);
  }
}

// ============================== launch ==============================
extern "C" void kernel_launch(void* const* d_in, const int* in_sizes, int n_in,
                              void* d_out, int out_size, void* d_ws, size_t ws_size,
                              hipStream_t stream) {
  (void)in_sizes; (void)n_in; (void)out_size; (void)ws_size;
  const float* voice    = (const float*)d_in[0];
  const float* cpc      = (const float*)d_in[1];
  const float* amps     = (const float*)d_in[2];
  const float* roomc    = (const float*)d_in[3];
  const float* roomm    = (const float*)d_in[4];
  const float* times    = (const float*)d_in[5];
  const float* cp_items = (const float*)d_in[6];
  const float* verbs    = (const float*)d_in[7];
  const float* w1       = (const float*)d_in[8];
  const float* w2       = (const float*)d_in[9];
  const float* amaps    = (const float*)d_in[10];
  const float* decays   = (const float*)d_in[11];
  const float* gains    = (const float*)d_in[12];
  const float* mix      = (const float*)d_in[13];
  float* out = (float*)d_out;

  // workspace layout:
  //   P:    4096 B
  //   twg:  8192 B (1024 float2)
  //   cp_out_all: 393216 f32
  //   mixed: 8388608 f32
  //   Shat: 64*128*1032 float2 (aliased as Ohat)
  //   Vhat: 8*128*1032 float2
  char* base = (char*)d_ws;
  EvParams* P       = (EvParams*)base;
  float2* twg       = (float2*)(base + 4096);
  float* cp_out_all = (float*)(base + 4096 + 8192);
  float* mixed      = cp_out_all + (size_t)393216;
  float2* Shat      = (float2*)(mixed + (size_t)8388608);
  float2* Vhat      = Shat + (size_t)NEV * NFR * NBP;
  float2* Ohat = Shat;   // safe: each K3 block reads only its own bins before writing them

  kt_tw<<<4, 256, 0, stream>>>(twg);
  kz_zero<<<(NEV * NS / 4) / 256, 256, 0, stream>>>((float4*)out);
  k0_params<<<NEV, 64, 0, stream>>>(voice, cpc, amps, roomc, roomm, mix, P);
  kv_fft<<<NVERB * NFR, 256, 0, stream>>>(verbs, twg, Vhat);
  k1a_synth<<<NEV, 256, 0, stream>>>(cp_items, w1, w2, decays, gains, P, cp_out_all);
  k1b_audio<<<NEV * 8, 256, 0, stream>>>(amaps, cp_out_all, P, mixed);
  k2_fwd<<<NEV * NFR, 256, 0, stream>>>(mixed, P, twg, Shat);
  k3_conv<<<NEV * 65, 256, 0, stream>>>(Shat, Vhat, times, P, Ohat);
  k4_ifft<<<NEV * NFR, 256, 0, stream>>>(Ohat, twg, out);
}

// Round 4
// 690.200 us; speedup vs baseline: 1.0614x; 1.0614x over previous
//
#include <hip/hip_runtime.h>
#include <math.h>

#define NS 131072
#define NFR 128
#define CPDIM 16
#define WIN 1024
#define NVOICE 8
#define NBLK 3
#define NCP 512
#define NVERB 8
#define NEV 64
#define N1 1024          // complex FFT length (real length 2048)
#define NBINS 1025
#define IDX(i) ((i) + ((i) >> 5))

struct EvParams {
  int vidx, cpidx, ridx;
  float vm0, vm1, amp;
  float mixw0, mixw1, mixw2;
  unsigned int maxslot;
  int pad[6];
}; // 64 bytes

// ============================== K_tw: twiddle table e^{-2pi i k/2048}, k=0..1023 ==============================
__global__ void kt_tw(float2* __restrict__ tw) {
  int k = blockIdx.x * 256 + threadIdx.x;
  if (k < 1024) {
    float ang = -3.067961575771282340e-03f * (float)k; // -2pi/2048
    float s, c;
    sincosf(ang, &s, &c);
    tw[k] = make_float2(c, s);
  }
}

// ============================== FFT-1024 stages (in-place, bit-reversed input, padded idx) ==============================
__device__ __forceinline__ void fft1024(float* re, float* im,
                                        const float* twr, const float* twi,
                                        int tid, bool inverse) {
  #pragma unroll
  for (int s = 1; s <= 10; ++s) {
    const int half = 1 << (s - 1);
    const int tsh = 11 - s;
    for (int k = tid; k < 512; k += 256) {
      int j = k & (half - 1);
      int i0 = ((k ^ j) << 1) | j;
      int i1 = IDX(i0 + half);
      i0 = IDX(i0);
      float wr = twr[j << tsh];
      float wi = twi[j << tsh];
      if (inverse) wi = -wi;
      float xr = re[i1], xi = im[i1];
      float tr = wr * xr - wi * xi;
      float ti = wr * xi + wi * xr;
      float ur = re[i0], ui = im[i0];
      re[i0] = ur + tr; im[i0] = ui + ti;
      re[i1] = ur - tr; im[i1] = ui - ti;
    }
    __syncthreads();
  }
}

// real-2048 forward FFT via packed complex-1024
__device__ __forceinline__ void rfft_fwd(const float2* __restrict__ src2, float scale,
                                         float2* __restrict__ dst,
                                         float* re, float* im, float* twr, float* twi,
                                         const float2* __restrict__ twg, int tid) {
  for (int i = tid; i < 1024; i += 256) { float2 w = twg[i]; twr[i] = w.x; twi[i] = w.y; }
  for (int n = tid; n < 1024; n += 256) {
    int r = IDX(__brev(n) >> 22);
    if (n < 512) {
      float2 x = src2[n];
      re[r] = x.x * scale; im[r] = x.y * scale;
    } else { re[r] = 0.0f; im[r] = 0.0f; }
  }
  __syncthreads();
  fft1024(re, im, twr, twi, tid, false);
  // untwist: X[k] = A + W_k B, W_k = e^{-i pi k/1024}
  for (int k = tid; k <= 1024; k += 256) {
    int km = (1024 - k) & 1023;
    float zr = re[IDX(k & 1023)], zi = im[IDX(k & 1023)];
    float mr = re[IDX(km)], mi = im[IDX(km)];
    float Are = 0.5f * (zr + mr), Aim = 0.5f * (zi - mi);
    float Bre = 0.5f * (zi + mi), Bim = 0.5f * (mr - zr);
    float wr, wi;
    if (k == 1024) { wr = -1.0f; wi = 0.0f; }
    else { wr = twr[k]; wi = twi[k]; }
    dst[k] = make_float2(Are + wr * Bre - wi * Bim, Aim + wr * Bim + wi * Bre);
  }
}

// ============================== K0: per-event params ==============================
__global__ void k0_params(const float* __restrict__ voice, const float* __restrict__ cpc,
                          const float* __restrict__ amps, const float* __restrict__ roomc,
                          const float* __restrict__ roomm, const float* __restrict__ mix,
                          EvParams* __restrict__ P) {
  int e = blockIdx.x;
  int tid = threadIdx.x; // 64 threads
  __shared__ float bvals[64];
  __shared__ int bidx[64];

  if (tid == 0) {
    const float* v = voice + e * NVOICE;
    int vi = 0; float bv = v[0];
    for (int i = 1; i < NVOICE; ++i) if (v[i] > bv) { bv = v[i]; vi = i; }
    P[e].vidx = vi;

    const float* r = roomc + e * NVERB;
    int ri = 0; float br = r[0];
    for (int i = 1; i < NVERB; ++i) if (r[i] > br) { br = r[i]; ri = i; }
    P[e].ridx = ri;

    float m0 = roomm[e * 2 + 0], m1 = roomm[e * 2 + 1];
    float mx = fmaxf(m0, m1);
    float e0 = expf(m0 - mx), e1 = expf(m1 - mx);
    float inv = 1.0f / (e0 + e1);
    P[e].vm0 = e0 * inv;
    P[e].vm1 = e1 * inv;
    P[e].amp = fabsf(amps[e]);

    const float* mm = mix + vi * NBLK;
    float mmx = fmaxf(fmaxf(mm[0], mm[1]), mm[2]);
    float w0 = expf(mm[0] - mmx), w1 = expf(mm[1] - mmx), w2 = expf(mm[2] - mmx);
    float si = 1.0f / (w0 + w1 + w2);
    P[e].mixw0 = w0 * si; P[e].mixw1 = w1 * si; P[e].mixw2 = w2 * si;
    P[e].maxslot = 0u;
  }

  const float* c = cpc + (size_t)e * NCP;
  float bv = -INFINITY; int bi = 0;
  for (int i = tid; i < NCP; i += 64) {
    float x = c[i];
    if (x > bv) { bv = x; bi = i; }
  }
  bvals[tid] = bv; bidx[tid] = bi;
  __syncthreads();
  if (tid == 0) {
    float best = bvals[0]; int besti = bidx[0];
    for (int i = 1; i < 64; ++i) {
      if (bvals[i] > best || (bvals[i] == best && bidx[i] < besti)) { best = bvals[i]; besti = bidx[i]; }
    }
    P[e].cpidx = besti;
  }
}

// ============================== Kv: verb chunk FFTs ==============================
__global__ __launch_bounds__(256) void kv_fft(const float* __restrict__ verbs,
                                              const float2* __restrict__ twg,
                                              float2* __restrict__ Vhat) {
  __shared__ float re[N1 + 32], im[N1 + 32];
  __shared__ float twr[N1], twi[N1];
  int v = blockIdx.x >> 7, j = blockIdx.x & 127;
  int tid = threadIdx.x;
  rfft_fwd((const float2*)(verbs + (size_t)v * NS + j * WIN), 1.0f,
           Vhat + ((size_t)v * NFR + j) * NBINS, re, im, twr, twi, twg, tid);
}

// ============================== K1a: recurrent synthesis ==============================
__global__ __launch_bounds__(256) void k1a_synth(const float* __restrict__ cp_items,
                                                 const float* __restrict__ w1_all,
                                                 const float* __restrict__ w2_all,
                                                 const float* __restrict__ decays,
                                                 const float* __restrict__ gains,
                                                 const EvParams* __restrict__ P,
                                                 float* __restrict__ cp_out_all) {
  __shared__ float wc[2048], xb[2048], yb[2048];
  __shared__ float w1s[256], w2s[256];
  __shared__ float dv[16], gv[16];
  __shared__ float rv[4];
  __shared__ int ri[4];
  __shared__ float s_scale;

  int e = blockIdx.x, tid = threadIdx.x;
  int vidx = P[e].vidx, cpidx = P[e].cpidx;
  int base = tid * 8;

  // load 8 values/thread into registers + block sum
  float vals[8];
  float ls = 0.0f;
  #pragma unroll
  for (int q = 0; q < 8; ++q) {
    float x = cp_items[(size_t)cpidx * 2048 + base + q];
    vals[q] = x; ls += x;
  }
  #pragma unroll
  for (int off = 32; off > 0; off >>= 1) ls += __shfl_xor(ls, off);
  if ((tid & 63) == 0) rv[tid >> 6] = ls;
  __syncthreads();
  if (tid == 0) s_scale = 1.0f / (rv[0] + rv[1] + rv[2] + rv[3] + 1e-8f);
  for (int i = tid; i < 2048; i += 256) wc[i] = 0.0f;
  __syncthreads();
  float scale = s_scale;

  // top-32 selection (register-resident, shuffle argmax, first-index tiebreak)
  for (int it = 0; it < 32; ++it) {
    float bv = -1.0f; int bi = 1 << 30;
    #pragma unroll
    for (int q = 0; q < 8; ++q) {
      if (vals[q] > bv) { bv = vals[q]; bi = base + q; }
    }
    #pragma unroll
    for (int off = 32; off > 0; off >>= 1) {
      float ov = __shfl_xor(bv, off); int oi = __shfl_xor(bi, off);
      if (ov > bv || (ov == bv && oi < bi)) { bv = ov; bi = oi; }
    }
    if ((tid & 63) == 0) { rv[tid >> 6] = bv; ri[tid >> 6] = bi; }
    __syncthreads();
    float wv = rv[0]; int wi = ri[0];
    #pragma unroll
    for (int w = 1; w < 4; ++w) {
      if (rv[w] > wv || (rv[w] == wv && ri[w] < wi)) { wv = rv[w]; wi = ri[w]; }
    }
    if ((wi >> 3) == tid) { vals[wi & 7] = -2.0f; wc[wi] = wv * scale; }
    __syncthreads();
  }

  for (int l = 0; l < NBLK; ++l) {
    int wbase = (vidx * NBLK + l) * 256;
    w1s[tid] = w1_all[wbase + tid];
    w2s[tid] = w2_all[wbase + tid];
    if (tid < 16) {
      float dp = decays[(vidx * NBLK + l) * 16 + tid];
      float sd = 1.0f / (1.0f + expf(-dp));
      dv[tid] = 1e-12f + 0.5f + 0.5f * sd;
      float gp = gains[(vidx * NBLK + l) * 16 + tid];
      gv[tid] = 5.0f / (1.0f + expf(-gp));
    }
    __syncthreads();
    for (int i = tid; i < 2048; i += 256) {
      int cch = i >> 7, f = i & 127;
      float acc = 0.0f;
      #pragma unroll
      for (int k = 0; k < 16; ++k) acc += w1s[cch * 16 + k] * fmaxf(wc[k * 128 + f], 0.0f);
      xb[i] = acc;
    }
    __syncthreads();
    if (tid < 16) {
      float a = 0.0f, d = dv[tid];
      for (int t = 0; t < 128; ++t) { a = d * (a + xb[tid * 128 + t]); yb[tid * 128 + t] = a; }
    }
    __syncthreads();
    for (int i = tid; i < 2048; i += 256) {
      int cch = i >> 7, f = i & 127;
      float acc = xb[i];
      #pragma unroll
      for (int k = 0; k < 16; ++k) acc += w2s[cch * 16 + k] * yb[k * 128 + f];
      float co = tanhf(acc * gv[cch]);
      wc[i] = co;
      cp_out_all[((size_t)e * NBLK + l) * 2048 + i] = co;
    }
    __syncthreads();
  }
}

// ============================== K1b: audio matmul + mix + maxabs ==============================
__global__ __launch_bounds__(256) void k1b_audio(const float* __restrict__ amaps,
                                                 const float* __restrict__ cp_out_all,
                                                 EvParams* __restrict__ P,
                                                 float* __restrict__ mixed) {
  __shared__ float cps[NBLK][16][16]; // [bl][c][fl]
  __shared__ float red[256];
  int e = blockIdx.x >> 3, fg = blockIdx.x & 7;
  int f0 = fg * 16, tid = threadIdx.x;
  int vidx = P[e].vidx;
  float mw[3] = {P[e].mixw0, P[e].mixw1, P[e].mixw2};

  for (int i = tid; i < NBLK * 256; i += 256) {
    int bl = i >> 8, r = i & 255, cch = r >> 4, fl = r & 15;
    cps[bl][cch][fl] = cp_out_all[((size_t)e * NBLK + bl) * 2048 + cch * 128 + f0 + fl];
  }
  __syncthreads();

  float amax = 0.0f;
  for (int jw = 0; jw < 4; ++jw) {
    int w = jw * 256 + tid;
    float am[NBLK][16];
    #pragma unroll
    for (int bl = 0; bl < NBLK; ++bl) {
      const float* ap = amaps + (((size_t)(vidx * NBLK + bl)) * WIN + w) * CPDIM;
      #pragma unroll
      for (int cch = 0; cch < 16; ++cch) am[bl][cch] = ap[cch] * mw[bl];
    }
    for (int fl = 0; fl < 16; ++fl) {
      float acc = 0.0f;
      #pragma unroll
      for (int bl = 0; bl < NBLK; ++bl)
        #pragma unroll
        for (int cch = 0; cch < 16; ++cch) acc += am[bl][cch] * cps[bl][cch][fl];
      mixed[(size_t)e * NS + (size_t)(f0 + fl) * WIN + w] = acc;
      amax = fmaxf(amax, fabsf(acc));
    }
  }
  red[tid] = amax;
  __syncthreads();
  for (int s = 128; s > 0; s >>= 1) { if (tid < s) red[tid] = fmaxf(red[tid], red[tid + s]); __syncthreads(); }
  if (tid == 0) atomicMax(&P[e].maxslot, __float_as_uint(red[0]));
}

// ============================== K2: forward chunk FFTs (unnormalized; 1/max folded into k3) ==============================
__global__ __launch_bounds__(256) void k2_fwd(const float* __restrict__ mixed,
                                              const float2* __restrict__ twg,
                                              float2* __restrict__ Shat) {
  __shared__ float re[N1 + 32], im[N1 + 32];
  __shared__ float twr[N1], twi[N1];
  int e = blockIdx.x >> 7, p = blockIdx.x & 127;
  int tid = threadIdx.x;
  rfft_fwd((const float2*)(mixed + (size_t)e * NS + p * WIN), 1.0f,
           Shat + ((size_t)e * NFR + p) * NBINS, re, im, twr, twi, twg, tid);
}

// ============================== K3: double triangular conv in chunk-frequency domain ==============================
// 16 bins/block; global stride NBINS (R2-proven); LDS float2 stride 17 (conflict-free)
__global__ __launch_bounds__(256, 4) void k3_conv(const float2* __restrict__ Shat,
                                                  const float2* __restrict__ Vhat,
                                                  const float* __restrict__ times_g,
                                                  const EvParams* __restrict__ P,
                                                  float2* __restrict__ Ohat) {
  __shared__ float2 S2[128 * 17];
  __shared__ float2 V2[128 * 17]; // reused as U after first conv
  __shared__ float tms[128];

  int bx = blockIdx.x;
  int e = bx / 65, bg = bx % 65;
  int bin0 = bg * 16;
  int tid = threadIdx.x;
  int b = tid & 15, pg = tid >> 4;
  int p0 = pg * 8;

  int ridx = P[e].ridx;
  float vm0 = P[e].vm0, vm1 = P[e].vm1;
  float amp = P[e].amp / (__uint_as_float(P[e].maxslot) + 1e-8f); // max_norm folded in

  const float2* Sg = Shat + (size_t)e * NFR * NBINS;
  const float2* Vg = Vhat + (size_t)ridx * NFR * NBINS;
  for (int i = tid; i < 2048; i += 256) {
    int f = i >> 4, bb = i & 15;
    int bin = bin0 + bb; if (bin > 1024) bin = 1024;
    S2[f * 17 + bb] = Sg[f * NBINS + bin];
    V2[f * 17 + bb] = Vg[f * NBINS + bin];
  }
  if (tid < 128) tms[tid] = times_g[e * NFR + tid];
  __syncthreads();

  // -------- first conv: G_p = sum_{f=0..p} S_f * V_{p-f}, p in [p0, p0+8) --------
  float ar[8], ai[8];
  #pragma unroll
  for (int t = 0; t < 8; ++t) { ar[t] = 0.0f; ai[t] = 0.0f; }

  for (int ft = 0; ft < pg; ++ft) {
    int f0v = ft * 8;
    float2 s[8];
    #pragma unroll
    for (int ff = 0; ff < 8; ++ff) s[ff] = S2[(f0v + ff) * 17 + b];
    float2 v[15];
    int jb = p0 - f0v - 7;
    #pragma unroll
    for (int m = 0; m < 15; ++m) v[m] = V2[(jb + m) * 17 + b];
    #pragma unroll
    for (int ff = 0; ff < 8; ++ff) {
      #pragma unroll
      for (int t = 0; t < 8; ++t) {
        int m = 7 - ff + t;
        ar[t] += s[ff].x * v[m].x - s[ff].y * v[m].y;
        ai[t] += s[ff].x * v[m].y + s[ff].y * v[m].x;
      }
    }
  }
  { // diagonal tile f in [p0, p0+7], constraint f <= p
    float2 s[8];
    #pragma unroll
    for (int ff = 0; ff < 8; ++ff) s[ff] = S2[(p0 + ff) * 17 + b];
    float2 v[8];
    #pragma unroll
    for (int m = 0; m < 8; ++m) v[m] = V2[m * 17 + b];
    #pragma unroll
    for (int ff = 0; ff < 8; ++ff) {
      #pragma unroll
      for (int t = 0; t < 8; ++t) {
        if (t >= ff) {
          int m = t - ff;
          ar[t] += s[ff].x * v[m].x - s[ff].y * v[m].y;
          ai[t] += s[ff].x * v[m].y + s[ff].y * v[m].x;
        }
      }
    }
  }

  // -------- U_p = amp*(vm0*G_p + vm1*S_p); store into V's LDS --------
  __syncthreads();
  #pragma unroll
  for (int t = 0; t < 8; ++t) {
    int p = p0 + t;
    float2 sv = S2[p * 17 + b];
    V2[p * 17 + b] = make_float2(amp * (vm0 * ar[t] + vm1 * sv.x),
                                 amp * (vm0 * ai[t] + vm1 * sv.y));
  }
  __syncthreads();

  // -------- second conv: O_p = sum_{r=0..p} times[r] * U_{p-r} --------
  #pragma unroll
  for (int t = 0; t < 8; ++t) { ar[t] = 0.0f; ai[t] = 0.0f; }

  for (int ft = 0; ft < pg; ++ft) {
    int f0v = ft * 8;
    float trr[8];
    #pragma unroll
    for (int ff = 0; ff < 8; ++ff) trr[ff] = tms[f0v + ff];
    float2 u[15];
    int jb = p0 - f0v - 7;
    #pragma unroll
    for (int m = 0; m < 15; ++m) u[m] = V2[(jb + m) * 17 + b];
    #pragma unroll
    for (int ff = 0; ff < 8; ++ff) {
      #pragma unroll
      for (int t = 0; t < 8; ++t) {
        int m = 7 - ff + t;
        ar[t] += trr[ff] * u[m].x;
        ai[t] += trr[ff] * u[m].y;
      }
    }
  }
  { // diagonal
    float trr[8];
    #pragma unroll
    for (int ff = 0; ff < 8; ++ff) trr[ff] = tms[p0 + ff];
    float2 u[8];
    #pragma unroll
    for (int m = 0; m < 8; ++m) u[m] = V2[m * 17 + b];
    #pragma unroll
    for (int ff = 0; ff < 8; ++ff) {
      #pragma unroll
      for (int t = 0; t < 8; ++t) {
        if (t >= ff) {
          int m = t - ff;
          ar[t] += trr[ff] * u[m].x;
          ai[t] += trr[ff] * u[m].y;
        }
      }
    }
  }

  int bin = bin0 + b;
  if (bin <= 1024) {
    float2* Og = Ohat + (size_t)e * NFR * NBINS;
    #pragma unroll
    for (int t = 0; t < 8; ++t) {
      Og[(p0 + t) * NBINS + bin] = make_float2(ar[t], ai[t]);
    }
  }
}

// ============================== K4: inverse real FFT + write halves ==============================
__global__ __launch_bounds__(256) void k4_ifft(const float2* __restrict__ Ohat,
                                               const float2* __restrict__ twg,
                                               float* __restrict__ out,
                                               float* __restrict__ tail) {
  __shared__ float re[N1 + 32], im[N1 + 32];
  __shared__ float twr[N1], twi[N1];
  int e = blockIdx.x >> 7, p = blockIdx.x & 127;
  int tid = threadIdx.x;
  const float2* src = Ohat + ((size_t)e * NFR + p) * NBINS;
  for (int i = tid; i < 1024; i += 256) { float2 w = twg[i]; twr[i] = w.x; twi[i] = w.y; }
  __syncthreads();
  // twist: Z[k] = A + iB
  for (int k = tid; k < 1024; k += 256) {
    float2 Xk = src[k];
    float2 Xm = src[1024 - k];
    float Are = 0.5f * (Xk.x + Xm.x), Aim = 0.5f * (Xk.y - Xm.y);
    float Dre = 0.5f * (Xk.x - Xm.x), Dim = 0.5f * (Xk.y + Xm.y);
    float wr = twr[k], wi = twi[k];
    float Bre = wr * Dre + wi * Dim;
    float Bim = wr * Dim - wi * Dre;
    int r = IDX(__brev(k) >> 22);
    re[r] = Are - Bim;
    im[r] = Aim + Bre;
  }
  __syncthreads();
  fft1024(re, im, twr, twi, tid, true);
  const float inv = 1.0f / (float)N1;
  // time sample 2n = re[n], 2n+1 = im[n]
  float2* o2 = (float2*)(out + (size_t)e * NS + (size_t)p * WIN);
  for (int n = tid; n < 512; n += 256) o2[n] = make_float2(re[IDX(n)] * inv, im[IDX(n)] * inv);
  float2* t2 = (float2*)(tail + ((size_t)e * NFR + p) * WIN);
  for (int n = tid; n < 512; n += 256) t2[n] = make_float2(re[IDX(n + 512)] * inv, im[IDX(n + 512)] * inv);
}

// ============================== K5: overlap-add tails ==============================
__global__ __launch_bounds__(256) void k5_tail(const float* __restrict__ tail, float* __restrict__ out) {
  size_t idx = (size_t)blockIdx.x * 256 + threadIdx.x;
  if (idx >= (size_t)NEV * 127 * WIN) return;
  int u = (int)(idx & 1023);
  size_t rest = idx >> 10;
  int pm1 = (int)(rest % 127);
  int e = (int)(rest / 127);
  int p = pm1 + 1;
  out[(size_t)e * NS + (size_t)p * WIN + u] += tail[((size_t)e * NFR + pm1) * WIN + u];
}

// ============================== launch ==============================
extern "C" void kernel_launch(void* const* d_in, const int* in_sizes, int n_in,
                              void* d_out, int out_size, void* d_ws, size_t ws_size,
                              hipStream_t stream) {
  (void)in_sizes; (void)n_in; (void)out_size; (void)ws_size;
  const float* voice    = (const float*)d_in[0];
  const float* cpc      = (const float*)d_in[1];
  const float* amps     = (const float*)d_in[2];
  const float* roomc    = (const float*)d_in[3];
  const float* roomm    = (const float*)d_in[4];
  const float* times    = (const float*)d_in[5];
  const float* cp_items = (const float*)d_in[6];
  const float* verbs    = (const float*)d_in[7];
  const float* w1       = (const float*)d_in[8];
  const float* w2       = (const float*)d_in[9];
  const float* amaps    = (const float*)d_in[10];
  const float* decays   = (const float*)d_in[11];
  const float* gains    = (const float*)d_in[12];
  const float* mix      = (const float*)d_in[13];
  float* out = (float*)d_out;

  // workspace layout:
  //   P:    4096 B
  //   twg:  8192 B (1024 float2)
  //   cp_out_all: 393216 f32
  //   mixed: 8388608 f32     (aliased as `tail` after K2 is done)
  //   Shat: 64*128*1025 float2 (aliased as Ohat; K3 blocks touch disjoint bins)
  //   Vhat: 8*128*1025 float2
  char* base = (char*)d_ws;
  EvParams* P       = (EvParams*)base;
  float2* twg       = (float2*)(base + 4096);
  float* cp_out_all = (float*)(base + 4096 + 8192);
  float* mixed      = cp_out_all + (size_t)393216;
  float2* Shat      = (float2*)(mixed + (size_t)8388608);
  float2* Vhat      = Shat + (size_t)NEV * NFR * NBINS;
  float* tail  = mixed;  // safe: mixed last read in K2; tail first written in K4
  float2* Ohat = Shat;   // safe: each K3 block reads only its own bins before writing them

  kt_tw<<<4, 256, 0, stream>>>(twg);
  k0_params<<<NEV, 64, 0, stream>>>(voice, cpc, amps, roomc, roomm, mix, P);
  kv_fft<<<NVERB * NFR, 256, 0, stream>>>(verbs, twg, Vhat);
  k1a_synth<<<NEV, 256, 0, stream>>>(cp_items, w1, w2, decays, gains, P, cp_out_all);
  k1b_audio<<<NEV * 8, 256, 0, stream>>>(amaps, cp_out_all, P, mixed);
  k2_fwd<<<NEV * NFR, 256, 0, stream>>>(mixed, twg, Shat);
  k3_conv<<<NEV * 65, 256, 0, stream>>>(Shat, Vhat, times, P, Ohat);
  k4_ifft<<<NEV * NFR, 256, 0, stream>>>(Ohat, twg, out, tail);
  k5_tail<<<(NEV * 127 * WIN) / 256, 256, 0, stream>>>(tail, out);
}

// Round 7
// 672.918 us; speedup vs baseline: 1.0887x; 1.0257x over previous
//
#include <hip/hip_runtime.h>
#include <math.h>

#define NS 131072
#define NFR 128
#define CPDIM 16
#define WIN 1024
#define NVOICE 8
#define NBLK 3
#define NCP 512
#define NVERB 8
#define NEV 64
#define N1 1024          // complex FFT length (real length 2048)
#define NBINS 1025
#define IDX(i) ((i) + ((i) >> 5))
#define VT_MAIN_BINS 1016   // bins [0,1016) of Vt live in d_out scratch; rest in ws

struct EvParams {
  int vidx, cpidx, ridx;
  float vm0, vm1, amp;
  float mixw0, mixw1, mixw2;
  unsigned int maxslot;
  int pad[6];
}; // 64 bytes

// ============================== K_tw: twiddle table e^{-2pi i k/2048}, k=0..1023 ==============================
__global__ void kt_tw(float2* __restrict__ tw) {
  int k = blockIdx.x * 256 + threadIdx.x;
  if (k < 1024) {
    float ang = -3.067961575771282340e-03f * (float)k; // -2pi/2048
    float s, c;
    sincosf(ang, &s, &c);
    tw[k] = make_float2(c, s);
  }
}

// ============================== FFT-1024 stages (in-place, bit-reversed input, padded idx) ==============================
__device__ __forceinline__ void fft1024(float* re, float* im,
                                        const float* twr, const float* twi,
                                        int tid, bool inverse) {
  #pragma unroll
  for (int s = 1; s <= 10; ++s) {
    const int half = 1 << (s - 1);
    const int tsh = 11 - s;
    for (int k = tid; k < 512; k += 256) {
      int j = k & (half - 1);
      int i0 = ((k ^ j) << 1) | j;
      int i1 = IDX(i0 + half);
      i0 = IDX(i0);
      float wr = twr[j << tsh];
      float wi = twi[j << tsh];
      if (inverse) wi = -wi;
      float xr = re[i1], xi = im[i1];
      float tr = wr * xr - wi * xi;
      float ti = wr * xi + wi * xr;
      float ur = re[i0], ui = im[i0];
      re[i0] = ur + tr; im[i0] = ui + ti;
      re[i1] = ur - tr; im[i1] = ui - ti;
    }
    __syncthreads();
  }
}

// real-2048 forward FFT via packed complex-1024
__device__ __forceinline__ void rfft_fwd(const float2* __restrict__ src2, float scale,
                                         float2* __restrict__ dst,
                                         float* re, float* im, float* twr, float* twi,
                                         const float2* __restrict__ twg, int tid) {
  for (int i = tid; i < 1024; i += 256) { float2 w = twg[i]; twr[i] = w.x; twi[i] = w.y; }
  for (int n = tid; n < 1024; n += 256) {
    int r = IDX(__brev(n) >> 22);
    if (n < 512) {
      float2 x = src2[n];
      re[r] = x.x * scale; im[r] = x.y * scale;
    } else { re[r] = 0.0f; im[r] = 0.0f; }
  }
  __syncthreads();
  fft1024(re, im, twr, twi, tid, false);
  // untwist: X[k] = A + W_k B, W_k = e^{-i pi k/1024}
  for (int k = tid; k <= 1024; k += 256) {
    int km = (1024 - k) & 1023;
    float zr = re[IDX(k & 1023)], zi = im[IDX(k & 1023)];
    float mr = re[IDX(km)], mi = im[IDX(km)];
    float Are = 0.5f * (zr + mr), Aim = 0.5f * (zi - mi);
    float Bre = 0.5f * (zi + mi), Bim = 0.5f * (mr - zr);
    float wr, wi;
    if (k == 1024) { wr = -1.0f; wi = 0.0f; }
    else { wr = twr[k]; wi = twi[k]; }
    dst[k] = make_float2(Are + wr * Bre - wi * Bim, Aim + wr * Bim + wi * Bre);
  }
}

// ============================== FFT-512 over NROWS rows (row stride 513 floats) ==============================
// forward DIT: input bit-reversed, output natural
template<int NROWS>
__device__ __forceinline__ void fft512_rows(float* re, float* im,
                                            const float* twr, const float* twi,
                                            int tid) {
  #pragma unroll
  for (int s = 1; s <= 9; ++s) {
    const int half = 1 << (s - 1);
    const int tsh = 9 - s;
    for (int q = tid; q < NROWS * 256; q += 256) {
      int row = q >> 8, k = q & 255;
      int j = k & (half - 1);
      int i0 = ((k ^ j) << 1) | j;
      int a0 = row * 513 + i0, a1 = a0 + half;
      float wr = twr[j << tsh];
      float wi = twi[j << tsh];
      float xr = re[a1], xi = im[a1];
      float tr = wr * xr - wi * xi;
      float ti = wr * xi + wi * xr;
      float ur = re[a0], ui = im[a0];
      re[a0] = ur + tr; im[a0] = ui + ti;
      re[a1] = ur - tr; im[a1] = ui - ti;
    }
    __syncthreads();
  }
}

// inverse DIF: input natural, output BIT-REVERSED (unscaled; gather with brev9)
template<int NROWS>
__device__ __forceinline__ void ifft512_rows_dif(float* re, float* im,
                                                 const float* twr, const float* twi,
                                                 int tid) {
  #pragma unroll
  for (int s = 9; s >= 1; --s) {
    const int half = 1 << (s - 1);
    const int tsh = 9 - s;
    for (int q = tid; q < NROWS * 256; q += 256) {
      int row = q >> 8, k = q & 255;
      int j = k & (half - 1);
      int i0 = ((k ^ j) << 1) | j;
      int a0 = row * 513 + i0, a1 = a0 + half;
      float wr = twr[j << tsh];
      float wi = -twi[j << tsh];  // conjugate
      float ur = re[a0], ui = im[a0];
      float vr = re[a1], vi = im[a1];
      re[a0] = ur + vr; im[a0] = ui + vi;
      float dr = ur - vr, di = ui - vi;
      re[a1] = dr * wr - di * wi;
      im[a1] = dr * wi + di * wr;
    }
    __syncthreads();
  }
}

// ============================== K0: per-event params ==============================
__global__ void k0_params(const float* __restrict__ voice, const float* __restrict__ cpc,
                          const float* __restrict__ amps, const float* __restrict__ roomc,
                          const float* __restrict__ roomm, const float* __restrict__ mix,
                          EvParams* __restrict__ P) {
  int e = blockIdx.x;
  int tid = threadIdx.x; // 64 threads
  __shared__ float bvals[64];
  __shared__ int bidx[64];

  if (tid == 0) {
    const float* v = voice + e * NVOICE;
    int vi = 0; float bv = v[0];
    for (int i = 1; i < NVOICE; ++i) if (v[i] > bv) { bv = v[i]; vi = i; }
    P[e].vidx = vi;

    const float* r = roomc + e * NVERB;
    int ri = 0; float br = r[0];
    for (int i = 1; i < NVERB; ++i) if (r[i] > br) { br = r[i]; ri = i; }
    P[e].ridx = ri;

    float m0 = roomm[e * 2 + 0], m1 = roomm[e * 2 + 1];
    float mx = fmaxf(m0, m1);
    float e0 = expf(m0 - mx), e1 = expf(m1 - mx);
    float inv = 1.0f / (e0 + e1);
    P[e].vm0 = e0 * inv;
    P[e].vm1 = e1 * inv;
    P[e].amp = fabsf(amps[e]);

    const float* mm = mix + vi * NBLK;
    float mmx = fmaxf(fmaxf(mm[0], mm[1]), mm[2]);
    float w0 = expf(mm[0] - mmx), w1 = expf(mm[1] - mmx), w2 = expf(mm[2] - mmx);
    float si = 1.0f / (w0 + w1 + w2);
    P[e].mixw0 = w0 * si; P[e].mixw1 = w1 * si; P[e].mixw2 = w2 * si;
    P[e].maxslot = 0u;
  }

  const float* c = cpc + (size_t)e * NCP;
  float bv = -INFINITY; int bi = 0;
  for (int i = tid; i < NCP; i += 64) {
    float x = c[i];
    if (x > bv) { bv = x; bi = i; }
  }
  bvals[tid] = bv; bidx[tid] = bi;
  __syncthreads();
  if (tid == 0) {
    float best = bvals[0]; int besti = bidx[0];
    for (int i = 1; i < 64; ++i) {
      if (bvals[i] > best || (bvals[i] == best && bidx[i] < besti)) { best = bvals[i]; besti = bidx[i]; }
    }
    P[e].cpidx = besti;
  }
}

// ============================== Kv: verb chunk FFTs ==============================
__global__ __launch_bounds__(256) void kv_fft(const float* __restrict__ verbs,
                                              const float2* __restrict__ twg,
                                              float2* __restrict__ Vhat) {
  __shared__ float re[N1 + 32], im[N1 + 32];
  __shared__ float twr[N1], twi[N1];
  int v = blockIdx.x >> 7, j = blockIdx.x & 127;
  int tid = threadIdx.x;
  rfft_fwd((const float2*)(verbs + (size_t)v * NS + j * WIN), 1.0f,
           Vhat + ((size_t)v * NFR + j) * NBINS, re, im, twr, twi, twg, tid);
}

// ============================== Kv2: chunk-axis FFT-512 of verb spectra ==============================
__global__ __launch_bounds__(256) void kv2_cfft(const float2* __restrict__ Vhat,
                                                const float2* __restrict__ twg,
                                                float2* __restrict__ VtMain,  // [v][1016][512]
                                                float2* __restrict__ VtRest) { // [v][9][512]
  __shared__ float zre[8 * 513], zim[8 * 513];
  __shared__ float twr[256], twi[256];
  int v = blockIdx.x / 129, bg = blockIdx.x % 129;
  int b0 = bg * 8;
  int tid = threadIdx.x;
  { float2 w = twg[4 * tid]; twr[tid] = w.x; twi[tid] = w.y; }
  const float2* Vg = Vhat + (size_t)v * NFR * NBINS;
  for (int idx = tid; idx < 1024; idx += 256) {
    int p = idx >> 3, bb = idx & 7;
    int bin = b0 + bb; if (bin > 1024) bin = 1024;
    float2 x = Vg[p * NBINS + bin];
    int r = __brev(p) >> 23;
    zre[bb * 513 + r] = x.x; zim[bb * 513 + r] = x.y;
  }
  for (int idx = tid; idx < 3072; idx += 256) {
    int p = 128 + (idx >> 3), bb = idx & 7;
    int r = __brev(p) >> 23;
    zre[bb * 513 + r] = 0.f; zim[bb * 513 + r] = 0.f;
  }
  __syncthreads();
  fft512_rows<8>(zre, zim, twr, twi, tid);
  for (int idx = tid; idx < 4096; idx += 256) {
    int bb = idx >> 9, c = idx & 511;
    int bin = b0 + bb;
    if (bin <= 1024) {
      float2 val = make_float2(zre[bb * 513 + c], zim[bb * 513 + c]);
      if (bin < VT_MAIN_BINS) VtMain[((size_t)v * VT_MAIN_BINS + bin) * 512 + c] = val;
      else VtRest[((size_t)v * 9 + (bin - VT_MAIN_BINS)) * 512 + c] = val;
    }
  }
}

// ============================== Kt: per-event times spectrum (FFT-512) ==============================
__global__ __launch_bounds__(256) void kt_times(const float* __restrict__ times_g,
                                                const float2* __restrict__ twg,
                                                float2* __restrict__ That) {
  __shared__ float re[513], im[513];
  __shared__ float twr[256], twi[256];
  int e = blockIdx.x, tid = threadIdx.x;
  { float2 w = twg[4 * tid]; twr[tid] = w.x; twi[tid] = w.y; }
  for (int p = tid; p < 512; p += 256) {
    int r = __brev(p) >> 23;
    float v = (p < 128) ? times_g[e * NFR + p] : 0.f;
    re[r] = v; im[r] = 0.f;
  }
  __syncthreads();
  fft512_rows<1>(re, im, twr, twi, tid);
  for (int c = tid; c < 512; c += 256) That[(size_t)e * 512 + c] = make_float2(re[c], im[c]);
}

// ============================== K1a: recurrent synthesis ==============================
__global__ __launch_bounds__(256) void k1a_synth(const float* __restrict__ cp_items,
                                                 const float* __restrict__ w1_all,
                                                 const float* __restrict__ w2_all,
                                                 const float* __restrict__ decays,
                                                 const float* __restrict__ gains,
                                                 const EvParams* __restrict__ P,
                                                 float* __restrict__ cp_out_all) {
  __shared__ float wc[2048], xb[2048], yb[2048];
  __shared__ float w1s[256], w2s[256];
  __shared__ float dv[16], gv[16];
  __shared__ float rv[4];
  __shared__ int ri[4];
  __shared__ float s_scale;

  int e = blockIdx.x, tid = threadIdx.x;
  int vidx = P[e].vidx, cpidx = P[e].cpidx;
  int base = tid * 8;

  float vals[8];
  float ls = 0.0f;
  #pragma unroll
  for (int q = 0; q < 8; ++q) {
    float x = cp_items[(size_t)cpidx * 2048 + base + q];
    vals[q] = x; ls += x;
  }
  #pragma unroll
  for (int off = 32; off > 0; off >>= 1) ls += __shfl_xor(ls, off);
  if ((tid & 63) == 0) rv[tid >> 6] = ls;
  __syncthreads();
  if (tid == 0) s_scale = 1.0f / (rv[0] + rv[1] + rv[2] + rv[3] + 1e-8f);
  for (int i = tid; i < 2048; i += 256) wc[i] = 0.0f;
  __syncthreads();
  float scale = s_scale;

  for (int it = 0; it < 32; ++it) {
    float bv = -1.0f; int bi = 1 << 30;
    #pragma unroll
    for (int q = 0; q < 8; ++q) {
      if (vals[q] > bv) { bv = vals[q]; bi = base + q; }
    }
    #pragma unroll
    for (int off = 32; off > 0; off >>= 1) {
      float ov = __shfl_xor(bv, off); int oi = __shfl_xor(bi, off);
      if (ov > bv || (ov == bv && oi < bi)) { bv = ov; bi = oi; }
    }
    if ((tid & 63) == 0) { rv[tid >> 6] = bv; ri[tid >> 6] = bi; }
    __syncthreads();
    float wv = rv[0]; int wi = ri[0];
    #pragma unroll
    for (int w = 1; w < 4; ++w) {
      if (rv[w] > wv || (rv[w] == wv && ri[w] < wi)) { wv = rv[w]; wi = ri[w]; }
    }
    if ((wi >> 3) == tid) { vals[wi & 7] = -2.0f; wc[wi] = wv * scale; }
    __syncthreads();
  }

  for (int l = 0; l < NBLK; ++l) {
    int wbase = (vidx * NBLK + l) * 256;
    w1s[tid] = w1_all[wbase + tid];
    w2s[tid] = w2_all[wbase + tid];
    if (tid < 16) {
      float dp = decays[(vidx * NBLK + l) * 16 + tid];
      float sd = 1.0f / (1.0f + expf(-dp));
      dv[tid] = 1e-12f + 0.5f + 0.5f * sd;
      float gp = gains[(vidx * NBLK + l) * 16 + tid];
      gv[tid] = 5.0f / (1.0f + expf(-gp));
    }
    __syncthreads();
    for (int i = tid; i < 2048; i += 256) {
      int cch = i >> 7, f = i & 127;
      float acc = 0.0f;
      #pragma unroll
      for (int k = 0; k < 16; ++k) acc += w1s[cch * 16 + k] * fmaxf(wc[k * 128 + f], 0.0f);
      xb[i] = acc;
    }
    __syncthreads();
    if (tid < 16) {
      float a = 0.0f, d = dv[tid];
      for (int t = 0; t < 128; ++t) { a = d * (a + xb[tid * 128 + t]); yb[tid * 128 + t] = a; }
    }
    __syncthreads();
    for (int i = tid; i < 2048; i += 256) {
      int cch = i >> 7, f = i & 127;
      float acc = xb[i];
      #pragma unroll
      for (int k = 0; k < 16; ++k) acc += w2s[cch * 16 + k] * yb[k * 128 + f];
      float co = tanhf(acc * gv[cch]);
      wc[i] = co;
      cp_out_all[((size_t)e * NBLK + l) * 2048 + i] = co;
    }
    __syncthreads();
  }
}

// ============================== K1b: audio matmul + mix + maxabs ==============================
__global__ __launch_bounds__(256) void k1b_audio(const float* __restrict__ amaps,
                                                 const float* __restrict__ cp_out_all,
                                                 EvParams* __restrict__ P,
                                                 float* __restrict__ mixed) {
  __shared__ float cps[NBLK][16][16]; // [bl][c][fl]
  __shared__ float red[256];
  int e = blockIdx.x >> 3, fg = blockIdx.x & 7;
  int f0 = fg * 16, tid = threadIdx.x;
  int vidx = P[e].vidx;
  float mw[3] = {P[e].mixw0, P[e].mixw1, P[e].mixw2};

  for (int i = tid; i < NBLK * 256; i += 256) {
    int bl = i >> 8, r = i & 255, cch = r >> 4, fl = r & 15;
    cps[bl][cch][fl] = cp_out_all[((size_t)e * NBLK + bl) * 2048 + cch * 128 + f0 + fl];
  }
  __syncthreads();

  float amax = 0.0f;
  for (int jw = 0; jw < 4; ++jw) {
    int w = jw * 256 + tid;
    float am[NBLK][16];
    #pragma unroll
    for (int bl = 0; bl < NBLK; ++bl) {
      const float* ap = amaps + (((size_t)(vidx * NBLK + bl)) * WIN + w) * CPDIM;
      #pragma unroll
      for (int cch = 0; cch < 16; ++cch) am[bl][cch] = ap[cch] * mw[bl];
    }
    for (int fl = 0; fl < 16; ++fl) {
      float acc = 0.0f;
      #pragma unroll
      for (int bl = 0; bl < NBLK; ++bl)
        #pragma unroll
        for (int cch = 0; cch < 16; ++cch) acc += am[bl][cch] * cps[bl][cch][fl];
      mixed[(size_t)e * NS + (size_t)(f0 + fl) * WIN + w] = acc;
      amax = fmaxf(amax, fabsf(acc));
    }
  }
  red[tid] = amax;
  __syncthreads();
  for (int s = 128; s > 0; s >>= 1) { if (tid < s) red[tid] = fmaxf(red[tid], red[tid + s]); __syncthreads(); }
  if (tid == 0) atomicMax(&P[e].maxslot, __float_as_uint(red[0]));
}

// ============================== K2: forward chunk FFTs (unnormalized; 1/max folded into k3) ==============================
__global__ __launch_bounds__(256) void k2_fwd(const float* __restrict__ mixed,
                                              const float2* __restrict__ twg,
                                              float2* __restrict__ Shat) {
  __shared__ float re[N1 + 32], im[N1 + 32];
  __shared__ float twr[N1], twi[N1];
  int e = blockIdx.x >> 7, p = blockIdx.x & 127;
  int tid = threadIdx.x;
  rfft_fwd((const float2*)(mixed + (size_t)e * NS + p * WIN), 1.0f,
           Shat + ((size_t)e * NFR + p) * NBINS, re, im, twr, twi, twg, tid);
}

// ============================== K3: chunk-axis FFT-512 pointwise convolution ==============================
// per block: 8 bins of one event; S in/out aliased (each block touches only its own bins)
__global__ __launch_bounds__(256) void k3_fft(float2* __restrict__ Shat,
                                              const float2* __restrict__ VtMain,
                                              const float2* __restrict__ VtRest,
                                              const float2* __restrict__ That,
                                              const float2* __restrict__ twg,
                                              const EvParams* __restrict__ P) {
  __shared__ float zre[8 * 513], zim[8 * 513];
  __shared__ float twr[256], twi[256];
  int e = blockIdx.x / 129, bg = blockIdx.x % 129;
  int b0 = bg * 8;
  int tid = threadIdx.x;
  int ridx = P[e].ridx;
  float vm0 = P[e].vm0, vm1 = P[e].vm1;
  float ampn = P[e].amp / (__uint_as_float(P[e].maxslot) + 1e-8f) * (1.0f / 512.0f);
  { float2 w = twg[4 * tid]; twr[tid] = w.x; twi[tid] = w.y; }

  float2* Sg = Shat + (size_t)e * NFR * NBINS;
  for (int idx = tid; idx < 1024; idx += 256) {
    int p = idx >> 3, bb = idx & 7;
    int bin = b0 + bb; if (bin > 1024) bin = 1024;
    float2 x = Sg[p * NBINS + bin];
    int r = __brev(p) >> 23;
    zre[bb * 513 + r] = x.x; zim[bb * 513 + r] = x.y;
  }
  for (int idx = tid; idx < 3072; idx += 256) {
    int p = 128 + (idx >> 3), bb = idx & 7;
    int r = __brev(p) >> 23;
    zre[bb * 513 + r] = 0.f; zim[bb * 513 + r] = 0.f;
  }
  __syncthreads();
  fft512_rows<8>(zre, zim, twr, twi, tid);   // natural-order spectrum in LDS

  // pointwise (natural order): z *= ampn * That[c] * (vm0*Vt[bin][c] + vm1)
  for (int idx = tid; idx < 4096; idx += 256) {
    int bb = idx >> 9, c = idx & 511;
    int bin = b0 + bb; if (bin > 1024) bin = 1024;
    float2 V = (bin < VT_MAIN_BINS) ? VtMain[((size_t)ridx * VT_MAIN_BINS + bin) * 512 + c]
                                    : VtRest[((size_t)ridx * 9 + (bin - VT_MAIN_BINS)) * 512 + c];
    float2 T = That[(size_t)e * 512 + c];
    float wr0 = vm0 * V.x + vm1, wi0 = vm0 * V.y;
    float wr = (wr0 * T.x - wi0 * T.y) * ampn;
    float wi = (wr0 * T.y + wi0 * T.x) * ampn;
    float zr = zre[bb * 513 + c], zi = zim[bb * 513 + c];
    zre[bb * 513 + c] = zr * wr - zi * wi;
    zim[bb * 513 + c] = zr * wi + zi * wr;
  }
  __syncthreads();
  ifft512_rows_dif<8>(zre, zim, twr, twi, tid);  // natural in -> BIT-REVERSED out

  for (int idx = tid; idx < 1024; idx += 256) {
    int p = idx >> 3, bb = idx & 7;
    int bin = b0 + bb;
    int r = __brev(p) >> 23;  // gather from bit-reversed position
    if (bin <= 1024) Sg[p * NBINS + bin] = make_float2(zre[bb * 513 + r], zim[bb * 513 + r]);
  }
}

// ============================== K4: inverse real FFT + write halves ==============================
__global__ __launch_bounds__(256) void k4_ifft(const float2* __restrict__ Ohat,
                                               const float2* __restrict__ twg,
                                               float* __restrict__ out,
                                               float* __restrict__ tail) {
  __shared__ float re[N1 + 32], im[N1 + 32];
  __shared__ float twr[N1], twi[N1];
  int e = blockIdx.x >> 7, p = blockIdx.x & 127;
  int tid = threadIdx.x;
  const float2* src = Ohat + ((size_t)e * NFR + p) * NBINS;
  for (int i = tid; i < 1024; i += 256) { float2 w = twg[i]; twr[i] = w.x; twi[i] = w.y; }
  __syncthreads();
  for (int k = tid; k < 1024; k += 256) {
    float2 Xk = src[k];
    float2 Xm = src[1024 - k];
    float Are = 0.5f * (Xk.x + Xm.x), Aim = 0.5f * (Xk.y - Xm.y);
    float Dre = 0.5f * (Xk.x - Xm.x), Dim = 0.5f * (Xk.y + Xm.y);
    float wr = twr[k], wi = twi[k];
    float Bre = wr * Dre + wi * Dim;
    float Bim = wr * Dim - wi * Dre;
    int r = IDX(__brev(k) >> 22);
    re[r] = Are - Bim;
    im[r] = Aim + Bre;
  }
  __syncthreads();
  fft1024(re, im, twr, twi, tid, true);
  const float inv = 1.0f / (float)N1;
  float2* o2 = (float2*)(out + (size_t)e * NS + (size_t)p * WIN);
  for (int n = tid; n < 512; n += 256) o2[n] = make_float2(re[IDX(n)] * inv, im[IDX(n)] * inv);
  float2* t2 = (float2*)(tail + ((size_t)e * NFR + p) * WIN);
  for (int n = tid; n < 512; n += 256) t2[n] = make_float2(re[IDX(n + 512)] * inv, im[IDX(n + 512)] * inv);
}

// ============================== K5: overlap-add tails ==============================
__global__ __launch_bounds__(256) void k5_tail(const float* __restrict__ tail, float* __restrict__ out) {
  size_t idx = (size_t)blockIdx.x * 256 + threadIdx.x;
  if (idx >= (size_t)NEV * 127 * WIN) return;
  int u = (int)(idx & 1023);
  size_t rest = idx >> 10;
  int pm1 = (int)(rest % 127);
  int e = (int)(rest / 127);
  int p = pm1 + 1;
  out[(size_t)e * NS + (size_t)p * WIN + u] += tail[((size_t)e * NFR + pm1) * WIN + u];
}

// ============================== launch ==============================
extern "C" void kernel_launch(void* const* d_in, const int* in_sizes, int n_in,
                              void* d_out, int out_size, void* d_ws, size_t ws_size,
                              hipStream_t stream) {
  (void)in_sizes; (void)n_in; (void)out_size; (void)ws_size;
  const float* voice    = (const float*)d_in[0];
  const float* cpc      = (const float*)d_in[1];
  const float* amps     = (const float*)d_in[2];
  const float* roomc    = (const float*)d_in[3];
  const float* roomm    = (const float*)d_in[4];
  const float* times    = (const float*)d_in[5];
  const float* cp_items = (const float*)d_in[6];
  const float* verbs    = (const float*)d_in[7];
  const float* w1       = (const float*)d_in[8];
  const float* w2       = (const float*)d_in[9];
  const float* amaps    = (const float*)d_in[10];
  const float* decays   = (const float*)d_in[11];
  const float* gains    = (const float*)d_in[12];
  const float* mix      = (const float*)d_in[13];
  float* out = (float*)d_out;

  // workspace layout — IDENTICAL total footprint to the R4 layout that ran:
  //   P:          4096
  //   twg:        8192           (1024 float2)
  //   cp_out_all: 1572864        (393216 f32; dead after k1b -> That/VtRest alias it)
  //   mixed:      33554432       (aliased as `tail` after K2)
  //   Shat:       67174400       (64x128x1025 float2; k3 in-place, k4 reads)
  //   Vhat:       8396800        (8x128x1025 float2)
  // That  (64x512 float2 = 262144 B) aliases cp_out_all[0..]      — written by kt_times AFTER k1b
  // VtRest(8x9x512 float2 = 294912 B) aliases cp_out_all[+262144] — written by kv2 AFTER k1b
  // VtMain (8x1016x512 float2 = 33.29 MB) lives in d_out scratch; d_out fully rewritten by k4/k5.
  char* base = (char*)d_ws;
  EvParams* P       = (EvParams*)base;
  float2* twg       = (float2*)(base + 4096);
  float* cp_out_all = (float*)(base + 4096 + 8192);
  float* mixed      = cp_out_all + (size_t)393216;
  float2* Shat      = (float2*)(mixed + (size_t)8388608);
  float2* Vhat      = Shat + (size_t)NEV * NFR * NBINS;
  float2* That      = (float2*)cp_out_all;
  float2* VtRest    = (float2*)((char*)cp_out_all + 262144);
  float2* VtMain    = (float2*)out;
  float* tail  = mixed;  // safe: mixed last read in K2; tail first written in K4
  float2* Ohat = Shat;   // safe: each K3 block reads only its own bins before writing them

  kt_tw<<<4, 256, 0, stream>>>(twg);
  k0_params<<<NEV, 64, 0, stream>>>(voice, cpc, amps, roomc, roomm, mix, P);
  kv_fft<<<NVERB * NFR, 256, 0, stream>>>(verbs, twg, Vhat);
  k1a_synth<<<NEV, 256, 0, stream>>>(cp_items, w1, w2, decays, gains, P, cp_out_all);
  k1b_audio<<<NEV * 8, 256, 0, stream>>>(amaps, cp_out_all, P, mixed);
  kv2_cfft<<<NVERB * 129, 256, 0, stream>>>(Vhat, twg, VtMain, VtRest);   // after k1b: aliases cp_out
  kt_times<<<NEV, 256, 0, stream>>>(times, twg, That);                     // after k1b: aliases cp_out
  k2_fwd<<<NEV * NFR, 256, 0, stream>>>(mixed, twg, Shat);
  k3_fft<<<NEV * 129, 256, 0, stream>>>(Shat, VtMain, VtRest, That, twg, P);
  k4_ifft<<<NEV * NFR, 256, 0, stream>>>(Ohat, twg, out, tail);
  k5_tail<<<(NEV * 127 * WIN) / 256, 256, 0, stream>>>(tail, out);
}

// Round 8
// 580.213 us; speedup vs baseline: 1.2626x; 1.1598x over previous
//
#include <hip/hip_runtime.h>
#include <math.h>

#define NS 131072
#define NFR 128
#define CPDIM 16
#define WIN 1024
#define NVOICE 8
#define NBLK 3
#define NCP 512
#define NVERB 8
#define NEV 64
#define N1 1024          // complex FFT length (real length 2048)
#define NBINS 1025
#define IDX(i) ((i) + ((i) >> 5))
#define VT_MAIN_BINS 1016   // bins [0,1016) of Vt live in d_out scratch; rest in ws

struct EvParams {
  int vidx, cpidx, ridx;
  float vm0, vm1, amp;
  float mixw0, mixw1, mixw2;
  unsigned int maxslot;
  int pad[6];
}; // 64 bytes

__device__ __forceinline__ float2 cmul(float2 a, float2 b) {
  return make_float2(a.x * b.x - a.y * b.y, a.x * b.y + a.y * b.x);
}
__device__ __forceinline__ float2 cadd(float2 a, float2 b) { return make_float2(a.x + b.x, a.y + b.y); }
__device__ __forceinline__ float2 csub(float2 a, float2 b) { return make_float2(a.x - b.x, a.y - b.y); }
__device__ __forceinline__ float2 cconj(float2 a) { return make_float2(a.x, -a.y); }

// ============================== K_tw: twiddle table e^{-2pi i k/2048}, k=0..1023 ==============================
__global__ void kt_tw(float2* __restrict__ tw) {
  int k = blockIdx.x * 256 + threadIdx.x;
  if (k < 1024) {
    float ang = -3.067961575771282340e-03f * (float)k; // -2pi/2048
    float s, c;
    sincosf(ang, &s, &c);
    tw[k] = make_float2(c, s);
  }
}

// ============================== FFT-1024 stages (in-place, bit-reversed input, padded idx) ==============================
__device__ __forceinline__ void fft1024(float* re, float* im,
                                        const float* twr, const float* twi,
                                        int tid, bool inverse) {
  #pragma unroll
  for (int s = 1; s <= 10; ++s) {
    const int half = 1 << (s - 1);
    const int tsh = 11 - s;
    for (int k = tid; k < 512; k += 256) {
      int j = k & (half - 1);
      int i0 = ((k ^ j) << 1) | j;
      int i1 = IDX(i0 + half);
      i0 = IDX(i0);
      float wr = twr[j << tsh];
      float wi = twi[j << tsh];
      if (inverse) wi = -wi;
      float xr = re[i1], xi = im[i1];
      float tr = wr * xr - wi * xi;
      float ti = wr * xi + wi * xr;
      float ur = re[i0], ui = im[i0];
      re[i0] = ur + tr; im[i0] = ui + ti;
      re[i1] = ur - tr; im[i1] = ui - ti;
    }
    __syncthreads();
  }
}

// real-2048 forward FFT via packed complex-1024
__device__ __forceinline__ void rfft_fwd(const float2* __restrict__ src2, float scale,
                                         float2* __restrict__ dst,
                                         float* re, float* im, float* twr, float* twi,
                                         const float2* __restrict__ twg, int tid) {
  for (int i = tid; i < 1024; i += 256) { float2 w = twg[i]; twr[i] = w.x; twi[i] = w.y; }
  for (int n = tid; n < 1024; n += 256) {
    int r = IDX(__brev(n) >> 22);
    if (n < 512) {
      float2 x = src2[n];
      re[r] = x.x * scale; im[r] = x.y * scale;
    } else { re[r] = 0.0f; im[r] = 0.0f; }
  }
  __syncthreads();
  fft1024(re, im, twr, twi, tid, false);
  // untwist: X[k] = A + W_k B, W_k = e^{-i pi k/1024}
  for (int k = tid; k <= 1024; k += 256) {
    int km = (1024 - k) & 1023;
    float zr = re[IDX(k & 1023)], zi = im[IDX(k & 1023)];
    float mr = re[IDX(km)], mi = im[IDX(km)];
    float Are = 0.5f * (zr + mr), Aim = 0.5f * (zi - mi);
    float Bre = 0.5f * (zi + mi), Bim = 0.5f * (mr - zr);
    float wr, wi;
    if (k == 1024) { wr = -1.0f; wi = 0.0f; }
    else { wr = twr[k]; wi = twi[k]; }
    dst[k] = make_float2(Are + wr * Bre - wi * Bim, Aim + wr * Bim + wi * Bre);
  }
}

// ============================== wave-level FFT-512 (8 float2/lane, n = 64r+lane) ==============================
// forward DIF: natural slots in -> bit-reversed slots out. inverse DIT: exact network inverse (x512).
struct Tw512 {
  float2 b64, t128_0, t128_1, t256_0, t256_1, t256_2, t256_3, t32, t16, t8, t4, t2;
};

__device__ __forceinline__ float2 eneg(float frac) { // e^{-pi i frac}
  float s, c; sincospif(frac, &s, &c); return make_float2(c, -s);
}

__device__ __forceinline__ Tw512 mk_tw512(int lane) {
  const float C = 0.70710678118654752f;
  Tw512 t;
  t.b64 = eneg((float)lane * (1.0f / 64.0f));
  float2 b128 = eneg((float)lane * (1.0f / 128.0f));
  t.t128_0 = b128;
  t.t128_1 = make_float2(b128.y, -b128.x);           // b128 * (-i)
  float2 b256 = eneg((float)lane * (1.0f / 256.0f));
  t.t256_0 = b256;
  t.t256_1 = cmul(b256, make_float2(C, -C));
  t.t256_2 = make_float2(b256.y, -b256.x);
  t.t256_3 = cmul(b256, make_float2(-C, -C));
  t.t32 = eneg((float)(lane & 31) * (1.0f / 32.0f));
  t.t16 = eneg((float)(lane & 15) * (1.0f / 16.0f));
  t.t8  = eneg((float)(lane & 7)  * (1.0f / 8.0f));
  int j4 = lane & 3;
  t.t4 = (j4 == 0) ? make_float2(1.f, 0.f) : (j4 == 1) ? make_float2(C, -C)
       : (j4 == 2) ? make_float2(0.f, -1.f) : make_float2(-C, -C);
  t.t2 = (lane & 1) ? make_float2(0.f, -1.f) : make_float2(1.f, 0.f);
  return t;
}

__device__ __forceinline__ void fwd_sh(float2* x, int h, float2 t, int lane) {
  bool hi = (lane & h) != 0;
  #pragma unroll
  for (int r = 0; r < 8; ++r) {
    float yr = __shfl_xor(x[r].x, h);
    float yi = __shfl_xor(x[r].y, h);
    float2 s = make_float2(x[r].x + yr, x[r].y + yi);
    float2 d = cmul(make_float2(yr - x[r].x, yi - x[r].y), t);
    x[r] = hi ? d : s;
  }
}

__device__ __forceinline__ void inv_sh(float2* x, int h, float2 tc, int lane) {
  bool hi = (lane & h) != 0;
  #pragma unroll
  for (int r = 0; r < 8; ++r) {
    float2 z = hi ? cmul(x[r], tc) : x[r];
    float zr = __shfl_xor(z.x, h);
    float zi = __shfl_xor(z.y, h);
    x[r] = hi ? make_float2(zr - z.x, zi - z.y) : make_float2(z.x + zr, z.y + zi);
  }
}

__device__ __forceinline__ void fft512_fwd(float2* x, const Tw512& T, int lane) {
  { // h=256: pairs (r, r+4)
    float2 u, v;
    u = x[0]; v = x[4]; x[0] = cadd(u, v); x[4] = cmul(csub(u, v), T.t256_0);
    u = x[1]; v = x[5]; x[1] = cadd(u, v); x[5] = cmul(csub(u, v), T.t256_1);
    u = x[2]; v = x[6]; x[2] = cadd(u, v); x[6] = cmul(csub(u, v), T.t256_2);
    u = x[3]; v = x[7]; x[3] = cadd(u, v); x[7] = cmul(csub(u, v), T.t256_3);
  }
  { // h=128: pairs (r, r+2), r in {0,1,4,5}
    float2 u, v;
    u = x[0]; v = x[2]; x[0] = cadd(u, v); x[2] = cmul(csub(u, v), T.t128_0);
    u = x[1]; v = x[3]; x[1] = cadd(u, v); x[3] = cmul(csub(u, v), T.t128_1);
    u = x[4]; v = x[6]; x[4] = cadd(u, v); x[6] = cmul(csub(u, v), T.t128_0);
    u = x[5]; v = x[7]; x[5] = cadd(u, v); x[7] = cmul(csub(u, v), T.t128_1);
  }
  #pragma unroll
  for (int r = 0; r < 8; r += 2) { // h=64
    float2 u = x[r], v = x[r + 1];
    x[r] = cadd(u, v); x[r + 1] = cmul(csub(u, v), T.b64);
  }
  fwd_sh(x, 32, T.t32, lane);
  fwd_sh(x, 16, T.t16, lane);
  fwd_sh(x, 8,  T.t8,  lane);
  fwd_sh(x, 4,  T.t4,  lane);
  fwd_sh(x, 2,  T.t2,  lane);
  fwd_sh(x, 1,  make_float2(1.f, 0.f), lane);
}

__device__ __forceinline__ void fft512_inv(float2* x, const Tw512& T, int lane) {
  inv_sh(x, 1,  make_float2(1.f, 0.f), lane);
  inv_sh(x, 2,  cconj(T.t2),  lane);
  inv_sh(x, 4,  cconj(T.t4),  lane);
  inv_sh(x, 8,  cconj(T.t8),  lane);
  inv_sh(x, 16, cconj(T.t16), lane);
  inv_sh(x, 32, cconj(T.t32), lane);
  #pragma unroll
  for (int r = 0; r < 8; r += 2) { // h=64
    float2 u = x[r], v = cmul(x[r + 1], cconj(T.b64));
    x[r] = cadd(u, v); x[r + 1] = csub(u, v);
  }
  { // h=128
    float2 u, v;
    u = x[0]; v = cmul(x[2], cconj(T.t128_0)); x[0] = cadd(u, v); x[2] = csub(u, v);
    u = x[1]; v = cmul(x[3], cconj(T.t128_1)); x[1] = cadd(u, v); x[3] = csub(u, v);
    u = x[4]; v = cmul(x[6], cconj(T.t128_0)); x[4] = cadd(u, v); x[6] = csub(u, v);
    u = x[5]; v = cmul(x[7], cconj(T.t128_1)); x[5] = cadd(u, v); x[7] = csub(u, v);
  }
  { // h=256
    float2 u, v;
    u = x[0]; v = cmul(x[4], cconj(T.t256_0)); x[0] = cadd(u, v); x[4] = csub(u, v);
    u = x[1]; v = cmul(x[5], cconj(T.t256_1)); x[1] = cadd(u, v); x[5] = csub(u, v);
    u = x[2]; v = cmul(x[6], cconj(T.t256_2)); x[2] = cadd(u, v); x[6] = csub(u, v);
    u = x[3]; v = cmul(x[7], cconj(T.t256_3)); x[3] = cadd(u, v); x[7] = csub(u, v);
  }
}

// ============================== K0: per-event params ==============================
__global__ void k0_params(const float* __restrict__ voice, const float* __restrict__ cpc,
                          const float* __restrict__ amps, const float* __restrict__ roomc,
                          const float* __restrict__ roomm, const float* __restrict__ mix,
                          EvParams* __restrict__ P) {
  int e = blockIdx.x;
  int tid = threadIdx.x; // 64 threads
  __shared__ float bvals[64];
  __shared__ int bidx[64];

  if (tid == 0) {
    const float* v = voice + e * NVOICE;
    int vi = 0; float bv = v[0];
    for (int i = 1; i < NVOICE; ++i) if (v[i] > bv) { bv = v[i]; vi = i; }
    P[e].vidx = vi;

    const float* r = roomc + e * NVERB;
    int ri = 0; float br = r[0];
    for (int i = 1; i < NVERB; ++i) if (r[i] > br) { br = r[i]; ri = i; }
    P[e].ridx = ri;

    float m0 = roomm[e * 2 + 0], m1 = roomm[e * 2 + 1];
    float mx = fmaxf(m0, m1);
    float e0 = expf(m0 - mx), e1 = expf(m1 - mx);
    float inv = 1.0f / (e0 + e1);
    P[e].vm0 = e0 * inv;
    P[e].vm1 = e1 * inv;
    P[e].amp = fabsf(amps[e]);

    const float* mm = mix + vi * NBLK;
    float mmx = fmaxf(fmaxf(mm[0], mm[1]), mm[2]);
    float w0 = expf(mm[0] - mmx), w1 = expf(mm[1] - mmx), w2 = expf(mm[2] - mmx);
    float si = 1.0f / (w0 + w1 + w2);
    P[e].mixw0 = w0 * si; P[e].mixw1 = w1 * si; P[e].mixw2 = w2 * si;
    P[e].maxslot = 0u;
  }

  const float* c = cpc + (size_t)e * NCP;
  float bv = -INFINITY; int bi = 0;
  for (int i = tid; i < NCP; i += 64) {
    float x = c[i];
    if (x > bv) { bv = x; bi = i; }
  }
  bvals[tid] = bv; bidx[tid] = bi;
  __syncthreads();
  if (tid == 0) {
    float best = bvals[0]; int besti = bidx[0];
    for (int i = 1; i < 64; ++i) {
      if (bvals[i] > best || (bvals[i] == best && bidx[i] < besti)) { best = bvals[i]; besti = bidx[i]; }
    }
    P[e].cpidx = besti;
  }
}

// ============================== Kv: verb chunk FFTs ==============================
__global__ __launch_bounds__(256) void kv_fft(const float* __restrict__ verbs,
                                              const float2* __restrict__ twg,
                                              float2* __restrict__ Vhat) {
  __shared__ float re[N1 + 32], im[N1 + 32];
  __shared__ float twr[N1], twi[N1];
  int v = blockIdx.x >> 7, j = blockIdx.x & 127;
  int tid = threadIdx.x;
  rfft_fwd((const float2*)(verbs + (size_t)v * NS + j * WIN), 1.0f,
           Vhat + ((size_t)v * NFR + j) * NBINS, re, im, twr, twi, twg, tid);
}

// ============================== Kv2: chunk-axis FFT-512 of verb spectra (register FFT) ==============================
__global__ __launch_bounds__(256) void kv2_reg(const float2* __restrict__ Vhat,
                                               float2* __restrict__ VtMain,  // [v][1016][512] slot order
                                               float2* __restrict__ VtRest) { // [v][9][512]
  __shared__ float2 tile[8][132];
  int v = blockIdx.x / 129, bg = blockIdx.x % 129;
  int b0 = bg * 8;
  int tid = threadIdx.x, lane = tid & 63, w = tid >> 6;

  const float2* Vg = Vhat + (size_t)v * NFR * NBINS;
  for (int idx = tid; idx < 1024; idx += 256) {
    int p = idx >> 3, bb = idx & 7;
    int bin = b0 + bb; if (bin > 1024) bin = 1024;
    tile[bb][p] = Vg[p * NBINS + bin];
  }
  __syncthreads();

  Tw512 T = mk_tw512(lane);
  for (int q = 0; q < 2; ++q) {
    int bb = w * 2 + q;
    int bin = b0 + bb;
    if (bin > 1024) continue;
    float2 xx[8];
    xx[0] = tile[bb][lane];
    xx[1] = tile[bb][64 + lane];
    #pragma unroll
    for (int r = 2; r < 8; ++r) xx[r] = make_float2(0.f, 0.f);
    fft512_fwd(xx, T, lane);
    float2* dst = (bin < VT_MAIN_BINS) ? (VtMain + ((size_t)v * VT_MAIN_BINS + bin) * 512)
                                       : (VtRest + ((size_t)v * 9 + (bin - VT_MAIN_BINS)) * 512);
    #pragma unroll
    for (int r = 0; r < 8; ++r) dst[64 * r + lane] = xx[r];
  }
}

// ============================== Kt: per-event times spectrum (register FFT-512, 1 wave/event) ==============================
__global__ __launch_bounds__(64) void kt_reg(const float* __restrict__ times_g,
                                             float2* __restrict__ That) {
  int e = blockIdx.x, lane = threadIdx.x;
  Tw512 T = mk_tw512(lane);
  float2 xx[8];
  xx[0] = make_float2(times_g[e * NFR + lane], 0.f);
  xx[1] = make_float2(times_g[e * NFR + 64 + lane], 0.f);
  #pragma unroll
  for (int r = 2; r < 8; ++r) xx[r] = make_float2(0.f, 0.f);
  fft512_fwd(xx, T, lane);
  #pragma unroll
  for (int r = 0; r < 8; ++r) That[(size_t)e * 512 + 64 * r + lane] = xx[r];
}

// ============================== K1a: recurrent synthesis ==============================
__global__ __launch_bounds__(256) void k1a_synth(const float* __restrict__ cp_items,
                                                 const float* __restrict__ w1_all,
                                                 const float* __restrict__ w2_all,
                                                 const float* __restrict__ decays,
                                                 const float* __restrict__ gains,
                                                 const EvParams* __restrict__ P,
                                                 float* __restrict__ cp_out_all) {
  __shared__ float wc[2048], xb[2048], yb[2048];
  __shared__ float w1s[256], w2s[256];
  __shared__ float dv[16], gv[16];
  __shared__ float rv[4];
  __shared__ int ri[4];
  __shared__ float s_scale;

  int e = blockIdx.x, tid = threadIdx.x;
  int vidx = P[e].vidx, cpidx = P[e].cpidx;
  int base = tid * 8;

  float vals[8];
  float ls = 0.0f;
  #pragma unroll
  for (int q = 0; q < 8; ++q) {
    float x = cp_items[(size_t)cpidx * 2048 + base + q];
    vals[q] = x; ls += x;
  }
  #pragma unroll
  for (int off = 32; off > 0; off >>= 1) ls += __shfl_xor(ls, off);
  if ((tid & 63) == 0) rv[tid >> 6] = ls;
  __syncthreads();
  if (tid == 0) s_scale = 1.0f / (rv[0] + rv[1] + rv[2] + rv[3] + 1e-8f);
  for (int i = tid; i < 2048; i += 256) wc[i] = 0.0f;
  __syncthreads();
  float scale = s_scale;

  for (int it = 0; it < 32; ++it) {
    float bv = -1.0f; int bi = 1 << 30;
    #pragma unroll
    for (int q = 0; q < 8; ++q) {
      if (vals[q] > bv) { bv = vals[q]; bi = base + q; }
    }
    #pragma unroll
    for (int off = 32; off > 0; off >>= 1) {
      float ov = __shfl_xor(bv, off); int oi = __shfl_xor(bi, off);
      if (ov > bv || (ov == bv && oi < bi)) { bv = ov; bi = oi; }
    }
    if ((tid & 63) == 0) { rv[tid >> 6] = bv; ri[tid >> 6] = bi; }
    __syncthreads();
    float wv = rv[0]; int wi = ri[0];
    #pragma unroll
    for (int w = 1; w < 4; ++w) {
      if (rv[w] > wv || (rv[w] == wv && ri[w] < wi)) { wv = rv[w]; wi = ri[w]; }
    }
    if ((wi >> 3) == tid) { vals[wi & 7] = -2.0f; wc[wi] = wv * scale; }
    __syncthreads();
  }

  for (int l = 0; l < NBLK; ++l) {
    int wbase = (vidx * NBLK + l) * 256;
    w1s[tid] = w1_all[wbase + tid];
    w2s[tid] = w2_all[wbase + tid];
    if (tid < 16) {
      float dp = decays[(vidx * NBLK + l) * 16 + tid];
      float sd = 1.0f / (1.0f + expf(-dp));
      dv[tid] = 1e-12f + 0.5f + 0.5f * sd;
      float gp = gains[(vidx * NBLK + l) * 16 + tid];
      gv[tid] = 5.0f / (1.0f + expf(-gp));
    }
    __syncthreads();
    for (int i = tid; i < 2048; i += 256) {
      int cch = i >> 7, f = i & 127;
      float acc = 0.0f;
      #pragma unroll
      for (int k = 0; k < 16; ++k) acc += w1s[cch * 16 + k] * fmaxf(wc[k * 128 + f], 0.0f);
      xb[i] = acc;
    }
    __syncthreads();
    if (tid < 16) {
      float a = 0.0f, d = dv[tid];
      for (int t = 0; t < 128; ++t) { a = d * (a + xb[tid * 128 + t]); yb[tid * 128 + t] = a; }
    }
    __syncthreads();
    for (int i = tid; i < 2048; i += 256) {
      int cch = i >> 7, f = i & 127;
      float acc = xb[i];
      #pragma unroll
      for (int k = 0; k < 16; ++k) acc += w2s[cch * 16 + k] * yb[k * 128 + f];
      float co = tanhf(acc * gv[cch]);
      wc[i] = co;
      cp_out_all[((size_t)e * NBLK + l) * 2048 + i] = co;
    }
    __syncthreads();
  }
}

// ============================== K1b: audio matmul + mix + maxabs ==============================
__global__ __launch_bounds__(256) void k1b_audio(const float* __restrict__ amaps,
                                                 const float* __restrict__ cp_out_all,
                                                 EvParams* __restrict__ P,
                                                 float* __restrict__ mixed) {
  __shared__ float cps[NBLK][16][16]; // [bl][c][fl]
  __shared__ float red[256];
  int e = blockIdx.x >> 3, fg = blockIdx.x & 7;
  int f0 = fg * 16, tid = threadIdx.x;
  int vidx = P[e].vidx;
  float mw[3] = {P[e].mixw0, P[e].mixw1, P[e].mixw2};

  for (int i = tid; i < NBLK * 256; i += 256) {
    int bl = i >> 8, r = i & 255, cch = r >> 4, fl = r & 15;
    cps[bl][cch][fl] = cp_out_all[((size_t)e * NBLK + bl) * 2048 + cch * 128 + f0 + fl];
  }
  __syncthreads();

  float amax = 0.0f;
  for (int jw = 0; jw < 4; ++jw) {
    int w = jw * 256 + tid;
    float am[NBLK][16];
    #pragma unroll
    for (int bl = 0; bl < NBLK; ++bl) {
      const float* ap = amaps + (((size_t)(vidx * NBLK + bl)) * WIN + w) * CPDIM;
      #pragma unroll
      for (int cch = 0; cch < 16; ++cch) am[bl][cch] = ap[cch] * mw[bl];
    }
    for (int fl = 0; fl < 16; ++fl) {
      float acc = 0.0f;
      #pragma unroll
      for (int bl = 0; bl < NBLK; ++bl)
        #pragma unroll
        for (int cch = 0; cch < 16; ++cch) acc += am[bl][cch] * cps[bl][cch][fl];
      mixed[(size_t)e * NS + (size_t)(f0 + fl) * WIN + w] = acc;
      amax = fmaxf(amax, fabsf(acc));
    }
  }
  red[tid] = amax;
  __syncthreads();
  for (int s = 128; s > 0; s >>= 1) { if (tid < s) red[tid] = fmaxf(red[tid], red[tid + s]); __syncthreads(); }
  if (tid == 0) atomicMax(&P[e].maxslot, __float_as_uint(red[0]));
}

// ============================== K2: forward chunk FFTs (unnormalized; 1/max folded into k3) ==============================
__global__ __launch_bounds__(256) void k2_fwd(const float* __restrict__ mixed,
                                              const float2* __restrict__ twg,
                                              float2* __restrict__ Shat) {
  __shared__ float re[N1 + 32], im[N1 + 32];
  __shared__ float twr[N1], twi[N1];
  int e = blockIdx.x >> 7, p = blockIdx.x & 127;
  int tid = threadIdx.x;
  rfft_fwd((const float2*)(mixed + (size_t)e * NS + p * WIN), 1.0f,
           Shat + ((size_t)e * NFR + p) * NBINS, re, im, twr, twi, twg, tid);
}

// ============================== K3: chunk-axis convolution via register FFT-512 ==============================
// per block: 8 bins of one event; each wave handles 2 bins fully in registers
__global__ __launch_bounds__(256) void k3_reg(float2* __restrict__ Shat,
                                              const float2* __restrict__ VtMain,
                                              const float2* __restrict__ VtRest,
                                              const float2* __restrict__ That,
                                              const EvParams* __restrict__ P) {
  __shared__ float2 tile[8][132];
  int e = blockIdx.x / 129, bg = blockIdx.x % 129;
  int b0 = bg * 8;
  int tid = threadIdx.x, lane = tid & 63, w = tid >> 6;
  int ridx = P[e].ridx;
  float vm0 = P[e].vm0, vm1 = P[e].vm1;
  float ampn = P[e].amp / (__uint_as_float(P[e].maxslot) + 1e-8f) * (1.0f / 512.0f);

  float2* Sg = Shat + (size_t)e * NFR * NBINS;
  for (int idx = tid; idx < 1024; idx += 256) {
    int p = idx >> 3, bb = idx & 7;
    int bin = b0 + bb; if (bin > 1024) bin = 1024;
    tile[bb][p] = Sg[p * NBINS + bin];
  }
  __syncthreads();

  Tw512 T = mk_tw512(lane);
  const float2* Trow = That + (size_t)e * 512;

  for (int q = 0; q < 2; ++q) {
    int bb = w * 2 + q;
    int bin = b0 + bb;
    int binc = bin > 1024 ? 1024 : bin;
    float2 xx[8];
    xx[0] = tile[bb][lane];
    xx[1] = tile[bb][64 + lane];
    #pragma unroll
    for (int r = 2; r < 8; ++r) xx[r] = make_float2(0.f, 0.f);
    fft512_fwd(xx, T, lane);

    const float2* Vrow = (binc < VT_MAIN_BINS) ? (VtMain + ((size_t)ridx * VT_MAIN_BINS + binc) * 512)
                                               : (VtRest + ((size_t)ridx * 9 + (binc - VT_MAIN_BINS)) * 512);
    #pragma unroll
    for (int r = 0; r < 8; ++r) {
      int n = 64 * r + lane;
      float2 V = Vrow[n];
      float2 Tt = Trow[n];
      float2 wv = make_float2(vm0 * V.x + vm1, vm0 * V.y);
      float2 wt = cmul(wv, Tt);
      wt.x *= ampn; wt.y *= ampn;
      xx[r] = cmul(xx[r], wt);
    }

    fft512_inv(xx, T, lane);
    tile[bb][lane] = xx[0];
    tile[bb][64 + lane] = xx[1];
  }
  __syncthreads();

  for (int idx = tid; idx < 1024; idx += 256) {
    int p = idx >> 3, bb = idx & 7;
    int bin = b0 + bb;
    if (bin <= 1024) Sg[p * NBINS + bin] = tile[bb][p];
  }
}

// ============================== K4: inverse real FFT + write halves ==============================
__global__ __launch_bounds__(256) void k4_ifft(const float2* __restrict__ Ohat,
                                               const float2* __restrict__ twg,
                                               float* __restrict__ out,
                                               float* __restrict__ tail) {
  __shared__ float re[N1 + 32], im[N1 + 32];
  __shared__ float twr[N1], twi[N1];
  int e = blockIdx.x >> 7, p = blockIdx.x & 127;
  int tid = threadIdx.x;
  const float2* src = Ohat + ((size_t)e * NFR + p) * NBINS;
  for (int i = tid; i < 1024; i += 256) { float2 w = twg[i]; twr[i] = w.x; twi[i] = w.y; }
  __syncthreads();
  for (int k = tid; k < 1024; k += 256) {
    float2 Xk = src[k];
    float2 Xm = src[1024 - k];
    float Are = 0.5f * (Xk.x + Xm.x), Aim = 0.5f * (Xk.y - Xm.y);
    float Dre = 0.5f * (Xk.x - Xm.x), Dim = 0.5f * (Xk.y + Xm.y);
    float wr = twr[k], wi = twi[k];
    float Bre = wr * Dre + wi * Dim;
    float Bim = wr * Dim - wi * Dre;
    int r = IDX(__brev(k) >> 22);
    re[r] = Are - Bim;
    im[r] = Aim + Bre;
  }
  __syncthreads();
  fft1024(re, im, twr, twi, tid, true);
  const float inv = 1.0f / (float)N1;
  float2* o2 = (float2*)(out + (size_t)e * NS + (size_t)p * WIN);
  for (int n = tid; n < 512; n += 256) o2[n] = make_float2(re[IDX(n)] * inv, im[IDX(n)] * inv);
  float2* t2 = (float2*)(tail + ((size_t)e * NFR + p) * WIN);
  for (int n = tid; n < 512; n += 256) t2[n] = make_float2(re[IDX(n + 512)] * inv, im[IDX(n + 512)] * inv);
}

// ============================== K5: overlap-add tails ==============================
__global__ __launch_bounds__(256) void k5_tail(const float* __restrict__ tail, float* __restrict__ out) {
  size_t idx = (size_t)blockIdx.x * 256 + threadIdx.x;
  if (idx >= (size_t)NEV * 127 * WIN) return;
  int u = (int)(idx & 1023);
  size_t rest = idx >> 10;
  int pm1 = (int)(rest % 127);
  int e = (int)(rest / 127);
  int p = pm1 + 1;
  out[(size_t)e * NS + (size_t)p * WIN + u] += tail[((size_t)e * NFR + pm1) * WIN + u];
}

// ============================== launch ==============================
extern "C" void kernel_launch(void* const* d_in, const int* in_sizes, int n_in,
                              void* d_out, int out_size, void* d_ws, size_t ws_size,
                              hipStream_t stream) {
  (void)in_sizes; (void)n_in; (void)out_size; (void)ws_size;
  const float* voice    = (const float*)d_in[0];
  const float* cpc      = (const float*)d_in[1];
  const float* amps     = (const float*)d_in[2];
  const float* roomc    = (const float*)d_in[3];
  const float* roomm    = (const float*)d_in[4];
  const float* times    = (const float*)d_in[5];
  const float* cp_items = (const float*)d_in[6];
  const float* verbs    = (const float*)d_in[7];
  const float* w1       = (const float*)d_in[8];
  const float* w2       = (const float*)d_in[9];
  const float* amaps    = (const float*)d_in[10];
  const float* decays   = (const float*)d_in[11];
  const float* gains    = (const float*)d_in[12];
  const float* mix      = (const float*)d_in[13];
  float* out = (float*)d_out;

  // workspace layout — IDENTICAL total footprint to the R4/R7 layout that ran:
  //   P:          4096
  //   twg:        8192           (1024 float2)
  //   cp_out_all: 1572864        (393216 f32; dead after k1b -> That/VtRest alias it)
  //   mixed:      33554432       (aliased as `tail` after K2)
  //   Shat:       67174400       (64x128x1025 float2; k3 in-place, k4 reads)
  //   Vhat:       8396800        (8x128x1025 float2)
  // That  (64x512 float2) aliases cp_out_all[0..]        — written by kt_reg AFTER k1b
  // VtRest(8x9x512 float2) aliases cp_out_all[+262144]   — written by kv2_reg AFTER k1b
  // VtMain (8x1016x512 float2 = 33.29 MB) lives in d_out scratch; d_out fully rewritten by k4/k5.
  char* base = (char*)d_ws;
  EvParams* P       = (EvParams*)base;
  float2* twg       = (float2*)(base + 4096);
  float* cp_out_all = (float*)(base + 4096 + 8192);
  float* mixed      = cp_out_all + (size_t)393216;
  float2* Shat      = (float2*)(mixed + (size_t)8388608);
  float2* Vhat      = Shat + (size_t)NEV * NFR * NBINS;
  float2* That      = (float2*)cp_out_all;
  float2* VtRest    = (float2*)((char*)cp_out_all + 262144);
  float2* VtMain    = (float2*)out;
  float* tail  = mixed;  // safe: mixed last read in K2; tail first written in K4
  float2* Ohat = Shat;   // safe: each K3 block reads only its own bins before writing them

  kt_tw<<<4, 256, 0, stream>>>(twg);
  k0_params<<<NEV, 64, 0, stream>>>(voice, cpc, amps, roomc, roomm, mix, P);
  kv_fft<<<NVERB * NFR, 256, 0, stream>>>(verbs, twg, Vhat);
  k1a_synth<<<NEV, 256, 0, stream>>>(cp_items, w1, w2, decays, gains, P, cp_out_all);
  k1b_audio<<<NEV * 8, 256, 0, stream>>>(amaps, cp_out_all, P, mixed);
  kv2_reg<<<NVERB * 129, 256, 0, stream>>>(Vhat, VtMain, VtRest);   // after k1b: aliases cp_out
  kt_reg<<<NEV, 64, 0, stream>>>(times, That);                      // after k1b: aliases cp_out
  k2_fwd<<<NEV * NFR, 256, 0, stream>>>(mixed, twg, Shat);
  k3_reg<<<NEV * 129, 256, 0, stream>>>(Shat, VtMain, VtRest, That, P);
  k4_ifft<<<NEV * NFR, 256, 0, stream>>>(Ohat, twg, out, tail);
  k5_tail<<<(NEV * 127 * WIN) / 256, 256, 0, stream>>>(tail, out);
}